// Round 1
// baseline (559.544 us; speedup 1.0000x reference)
//
#include <hip/hip_runtime.h>
#include <hip/hip_bf16.h>
#include <math.h>

// Problem constants (fixed shapes)
#define SS   2048   // sequence length
#define EE   2048   // embed dim
#define HH   16     // heads
#define QLAT 1536   // q latent
#define KLAT 512    // kv latent
#define DN   128
#define DR   64
#define DV   128
#define DQ   192    // DN+DR
#define KVD  256    // DN+DV
#define CKVW 576    // KLAT+DR
#define QW   3072   // HH*DQ
#define KVW  4096   // HH*KVD
#define OW   2048   // HH*DV
#define QAC  2112   // QLAT + CKVW (merged a-proj output width)

#define NSEG 4      // key segments (flash-decoding split)
#define SEGK 512    // keys per segment
#define PT_STRIDE 72

typedef __attribute__((ext_vector_type(8))) short short8;
typedef __attribute__((ext_vector_type(4))) float f32x4;

// ---------------- helpers ----------------
__global__ void detect_dtype(const unsigned int* __restrict__ lnw, int* flag) {
    *flag = (lnw[0] == 0x3F803F80u) ? 1 : 0;  // bf16 pair of 1.0 vs fp32 1.0
}

__device__ __forceinline__ float ld_in(const void* p, size_t i, int bf) {
    if (bf) return __bfloat162float(((const __hip_bfloat16*)p)[i]);
    return ((const float*)p)[i];
}

__device__ __forceinline__ ushort f2b(float v) {
    __hip_bfloat16 b = __float2bfloat16(v);
    return *(ushort*)&b;
}
__device__ __forceinline__ float b2f(ushort u) {
    __hip_bfloat16 b = *(__hip_bfloat16*)&u;
    return __bfloat162float(b);
}

// async global->LDS, 16 B per lane; LDS dst must be wave-uniform base + lane*16
__device__ __forceinline__ void async16(const ushort* g, ushort* l) {
    __builtin_amdgcn_global_load_lds(
        (const __attribute__((address_space(1))) void*)g,
        (__attribute__((address_space(3))) void*)l, 16, 0, 0);
}

// ---------------- input convert (x -> bf16) ----------------
__global__ __launch_bounds__(256) void conv_x_bf(
    const void* __restrict__ src, ushort* __restrict__ dst, int n, const int* flag) {
    const int bf = *flag;
    int i = (blockIdx.x * 256 + threadIdx.x) * 4;
    if (i >= n) return;
    ushort4 u;
    u.x = f2b(ld_in(src, i + 0, bf));
    u.y = f2b(ld_in(src, i + 1, bf));
    u.z = f2b(ld_in(src, i + 2, bf));
    u.w = f2b(ld_in(src, i + 3, bf));
    *(ushort4*)(dst + i) = u;
}

// ---------------- weight transpose+convert: in[R][C] -> out[C][R] bf16 ----------------
__global__ __launch_bounds__(256) void transpose_bf(
    const void* __restrict__ in, ushort* __restrict__ out,
    int R, int C, const int* flag) {
    const int bf = *flag;
    __shared__ ushort t[64][66];
    const int c0 = blockIdx.x * 64, r0 = blockIdx.y * 64;
    const int lane = threadIdx.x & 63, grp = threadIdx.x >> 6;
    #pragma unroll
    for (int p = 0; p < 16; ++p) {
        int r = p * 4 + grp;
        t[lane][r] = f2b(ld_in(in, (size_t)(r0 + r) * C + c0 + lane, bf));
    }
    __syncthreads();
    const int ro = (threadIdx.x & 31) * 2, co = threadIdx.x >> 5;
    #pragma unroll
    for (int p = 0; p < 8; ++p) {
        int c = p * 8 + co;
        ushort2 u = *(const ushort2*)&t[c][ro];
        *(ushort2*)&out[(size_t)(c0 + c) * R + r0 + ro] = u;
    }
}

// ---------------- bf16 MFMA GEMM 128x128: C[M][N] = A[M][K] @ Bt[N][K]^T ----------------
__global__ __launch_bounds__(256) void gemm_bf(
    const ushort* __restrict__ A, const ushort* __restrict__ Bt,
    void* __restrict__ C, int N, int K, int lda, int ldb, int ldc,
    int cmode, const int* __restrict__ cflag) {
    __shared__ ushort As[128 * 32];
    __shared__ ushort Bs[128 * 32];
    const int tid = threadIdx.x;
    const int bm = blockIdx.y * 128, bn = blockIdx.x * 128;
    const int lane = tid & 63, wv = tid >> 6;
    const int wm = (wv & 1) * 64, wn = (wv >> 1) * 64;
    const int ln = lane & 15, quad = lane >> 4;

    f32x4 acc[4][4];
    #pragma unroll
    for (int i = 0; i < 4; ++i)
        #pragma unroll
        for (int j = 0; j < 4; ++j) acc[i][j] = (f32x4){0.f, 0.f, 0.f, 0.f};

    const int srow = tid >> 2;
    const int spart = (((tid & 3) ^ ((tid >> 3) & 3))) * 8;  // swizzled source 16B part
    const ushort* Ag0 = A  + (size_t)(bm + srow) * lda + spart;
    const ushort* Ag1 = Ag0 + (size_t)64 * lda;
    const ushort* Bg0 = Bt + (size_t)(bn + srow) * ldb + spart;
    const ushort* Bg1 = Bg0 + (size_t)64 * ldb;
    ushort* Asl = As + tid * 8;
    ushort* Bsl = Bs + tid * 8;
    const bool bok0 = (bn + srow) < N;
    const bool bok1 = (bn + 64 + srow) < N;
    const int swq = (quad ^ ((ln >> 1) & 3)) * 8;  // swizzled read part

    for (int k0 = 0; k0 < K; k0 += 32) {
        async16(Ag0 + k0, Asl);
        async16(Ag1 + k0, Asl + 2048);
        if (bok0) async16(Bg0 + k0, Bsl);
        if (bok1) async16(Bg1 + k0, Bsl + 2048);
        __syncthreads();
        short8 af[4], bfr[4];
        #pragma unroll
        for (int t = 0; t < 4; ++t) {
            af[t]  = *(const short8*)&As[(wm + t * 16 + ln) * 32 + swq];
            bfr[t] = *(const short8*)&Bs[(wn + t * 16 + ln) * 32 + swq];
        }
        #pragma unroll
        for (int i = 0; i < 4; ++i)
            #pragma unroll
            for (int j = 0; j < 4; ++j)
                acc[i][j] = __builtin_amdgcn_mfma_f32_16x16x32_bf16(af[i], bfr[j], acc[i][j], 0, 0, 0);
        __syncthreads();
    }

    const int cbf = (cmode == 2) ? *cflag : cmode;
    #pragma unroll
    for (int i = 0; i < 4; ++i) {
        #pragma unroll
        for (int r = 0; r < 4; ++r) {
            const int m = bm + wm + i * 16 + quad * 4 + r;
            #pragma unroll
            for (int j = 0; j < 4; ++j) {
                const int n = bn + wn + j * 16 + ln;
                if (n < N) {
                    if (cbf) ((ushort*)C)[(size_t)m * ldc + n] = f2b(acc[i][j][r]);
                    else     ((float*)C)[(size_t)m * ldc + n] = acc[i][j][r];
                }
            }
        }
    }
}

// ---------------- bf16 MFMA GEMM 64x128 (small-grid variant) ----------------
__global__ __launch_bounds__(256) void gemm_bf64(
    const ushort* __restrict__ A, const ushort* __restrict__ Bt,
    void* __restrict__ C, int N, int K, int lda, int ldb, int ldc,
    int cmode, const int* __restrict__ cflag) {
    __shared__ ushort As[64 * 32];
    __shared__ ushort Bs[128 * 32];
    const int tid = threadIdx.x;
    const int bm = blockIdx.y * 64, bn = blockIdx.x * 128;
    const int lane = tid & 63, wv = tid >> 6;
    const int wm = (wv & 1) * 32, wn = (wv >> 1) * 64;
    const int ln = lane & 15, quad = lane >> 4;

    f32x4 acc[2][4];
    #pragma unroll
    for (int i = 0; i < 2; ++i)
        #pragma unroll
        for (int j = 0; j < 4; ++j) acc[i][j] = (f32x4){0.f, 0.f, 0.f, 0.f};

    const int srow = tid >> 2;
    const int spart = (((tid & 3) ^ ((tid >> 3) & 3))) * 8;
    const ushort* Ag0 = A  + (size_t)(bm + srow) * lda + spart;
    const ushort* Bg0 = Bt + (size_t)(bn + srow) * ldb + spart;
    const ushort* Bg1 = Bg0 + (size_t)64 * ldb;
    ushort* Asl = As + tid * 8;
    ushort* Bsl = Bs + tid * 8;
    const bool bok0 = (bn + srow) < N;
    const bool bok1 = (bn + 64 + srow) < N;
    const int swq = (quad ^ ((ln >> 1) & 3)) * 8;

    for (int k0 = 0; k0 < K; k0 += 32) {
        async16(Ag0 + k0, Asl);
        if (bok0) async16(Bg0 + k0, Bsl);
        if (bok1) async16(Bg1 + k0, Bsl + 2048);
        __syncthreads();
        short8 af[2], bfr[4];
        #pragma unroll
        for (int t = 0; t < 2; ++t)
            af[t] = *(const short8*)&As[(wm + t * 16 + ln) * 32 + swq];
        #pragma unroll
        for (int t = 0; t < 4; ++t)
            bfr[t] = *(const short8*)&Bs[(wn + t * 16 + ln) * 32 + swq];
        #pragma unroll
        for (int i = 0; i < 2; ++i)
            #pragma unroll
            for (int j = 0; j < 4; ++j)
                acc[i][j] = __builtin_amdgcn_mfma_f32_16x16x32_bf16(af[i], bfr[j], acc[i][j], 0, 0, 0);
        __syncthreads();
    }

    const int cbf = (cmode == 2) ? *cflag : cmode;
    #pragma unroll
    for (int i = 0; i < 2; ++i) {
        #pragma unroll
        for (int r = 0; r < 4; ++r) {
            const int m = bm + wm + i * 16 + quad * 4 + r;
            #pragma unroll
            for (int j = 0; j < 4; ++j) {
                const int n = bn + wn + j * 16 + ln;
                if (n < N) {
                    if (cbf) ((ushort*)C)[(size_t)m * ldc + n] = f2b(acc[i][j][r]);
                    else     ((float*)C)[(size_t)m * ldc + n] = acc[i][j][r];
                }
            }
        }
    }
}

// ---------------- RMSNorm bf16 in-place (fp32 math) ----------------
__global__ __launch_bounds__(256) void rmsnorm_bf(
    ushort* __restrict__ x, const void* __restrict__ w,
    int cols, int stride, const int* wflag) {
    const int wbf = *wflag;
    ushort* p = x + (size_t)blockIdx.x * stride;
    float ss = 0.f;
    for (int i = threadIdx.x; i < cols; i += 256) { float v = b2f(p[i]); ss += v * v; }
    #pragma unroll
    for (int off = 32; off; off >>= 1) ss += __shfl_xor(ss, off);
    __shared__ float red[4];
    const int wid = threadIdx.x >> 6, lane = threadIdx.x & 63;
    if (lane == 0) red[wid] = ss;
    __syncthreads();
    const float tot = red[0] + red[1] + red[2] + red[3];
    const float scale = rsqrtf(tot / (float)cols + 1e-6f);
    for (int i = threadIdx.x; i < cols; i += 256)
        p[i] = f2b(b2f(p[i]) * scale * ld_in(w, i, wbf));
}

// ---------------- RoPE (fp32 math on bf16 data) ----------------
__device__ __forceinline__ void rope64(const float* in, float t, float* out) {
    #pragma unroll
    for (int i = 0; i < 32; ++i) {
        float inv = powf(10000.0f, -(float)i / 32.0f);
        float sv, cv;
        sincosf(t * inv, &sv, &cv);
        float x0 = in[2 * i], x1 = in[2 * i + 1];
        out[i]      = x0 * cv - x1 * sv;
        out[i + 32] = x1 * cv + x0 * sv;
    }
}

__global__ void rope_q_bf(ushort* __restrict__ q) {
    int idx = blockIdx.x * blockDim.x + threadIdx.x;
    if (idx >= SS * HH) return;
    int s = idx >> 4, h = idx & 15;
    ushort* p = q + (size_t)s * QW + h * DQ + DN;
    float buf[DR], out[DR];
    #pragma unroll
    for (int i = 0; i < DR; ++i) buf[i] = b2f(p[i]);
    rope64(buf, (float)s, out);
    #pragma unroll
    for (int i = 0; i < DR; ++i) p[i] = f2b(out[i]);
}

__global__ void rope_k_bf(const ushort* __restrict__ ckv, ushort* __restrict__ kpe,
                          int stride) {
    int s = blockIdx.x * blockDim.x + threadIdx.x;
    if (s >= SS) return;
    const ushort* p = ckv + (size_t)s * stride + KLAT;
    float buf[DR], out[DR];
    #pragma unroll
    for (int i = 0; i < DR; ++i) buf[i] = b2f(p[i]);
    rope64(buf, (float)s, out);
    ushort* dp = kpe + (size_t)s * DR;
    #pragma unroll
    for (int i = 0; i < DR; ++i) dp[i] = f2b(out[i]);
}

// ---------------- build head-major K-full: kf[h][s][192] ----------------
__global__ __launch_bounds__(256) void build_kf(
    const ushort* __restrict__ kv, const ushort* __restrict__ kpe,
    ushort* __restrict__ kf) {
    int idx = blockIdx.x * 256 + threadIdx.x;       // SS*HH*24 items
    int part = idx % 24;
    int rest = idx / 24;
    int h = rest & 15, s = rest >> 4;
    short8 v;
    if (part < 16) v = *(const short8*)(kv + (size_t)s * KVW + h * KVD + part * 8);
    else           v = *(const short8*)(kpe + (size_t)s * DR + (part - 16) * 8);
    *(short8*)(kf + ((size_t)h * SS + s) * 192 + part * 8) = v;
}

// ---------------- build frag-ordered V: vt2[h][ck][idx2=kb2*8+nb][lane][8] ----------------
__global__ __launch_bounds__(256) void build_vt2(
    const ushort* __restrict__ kv, ushort* __restrict__ vt2) {
    __shared__ ushort Vl[64 * 136];
    const int ck = blockIdx.x, h = blockIdx.y;
    const int tid = threadIdx.x;
    const int lane = tid & 63, wv = tid >> 6;
    #pragma unroll
    for (int rr = 0; rr < 4; ++rr) {
        int n = rr * 256 + tid;
        int key = n >> 4, part = n & 15;
        short8 v = *(const short8*)(kv + (size_t)(ck * 64 + key) * KVW + h * KVD + DN + part * 8);
        *(short8*)&Vl[key * 136 + part * 8] = v;
    }
    __syncthreads();
    const int ln = lane & 15, quad = lane >> 4;
    ushort* dst = vt2 + (((size_t)h * 32 + ck) * 16) * 512;
    #pragma unroll
    for (int w = 0; w < 4; ++w) {
        int idx2 = wv * 4 + w;
        int kb2 = idx2 >> 3, nb = idx2 & 7;
        short8 v;
        #pragma unroll
        for (int j = 0; j < 8; ++j)
            ((ushort*)&v)[j] = Vl[(kb2 * 32 + quad * 8 + j) * 136 + nb * 16 + ln];
        *(short8*)(dst + (size_t)idx2 * 512 + lane * 8) = v;
    }
}

// ---------------- split-K MFMA flash attention ----------------
// v2 changes vs baseline (latency-bound: MfmaUtil 8.7%, Occ 19%):
//  (a) balanced contiguous chunk split: seg s covers chunks
//      [floor(s*ctot/4), floor((s+1)*ctot/4)) of the ctot=bq+1 causal chunks
//      -> max chunks/block drops 8-with-long-tail to ceil(ctot/4)
//  (b) reg-staged K prefetch (T14): next chunk's K-tile loaded into VGPRs
//      during compute; ds_write at top of next iter. Raw s_barrier +
//      explicit lgkmcnt(0) so prefetch loads stay in flight across the
//      barrier (no vmcnt(0) drain as __syncthreads would emit).
__global__ __launch_bounds__(256, 4) void attn_mfma2(
    const ushort* __restrict__ qbf, const ushort* __restrict__ kf,
    const ushort* __restrict__ vt2, ushort* __restrict__ opart,
    float* __restrict__ ml) {
    const int seg = blockIdx.x, bq = 31 - blockIdx.y, h = blockIdx.z;
    const int ctot = bq + 1;
    const int c_lo = (seg * ctot) >> 2;
    const int nch = (((seg + 1) * ctot) >> 2) - c_lo;
    if (nch <= 0) return;

    __shared__ ushort Kt[6 * 64 * 32];           // 24576 B
    __shared__ ushort Pt[4][16 * PT_STRIDE];     // 9216 B

    const int tid = threadIdx.x, lane = tid & 63, wl = tid >> 6;
    const int ln = lane & 15, quad = lane >> 4;
    const int qw = bq * 64 + wl * 16;
    const int kstart = c_lo << 6;
    const float scale = 0.07216878364870322f;  // 1/sqrt(192)

    short8 aq[6];
    const ushort* qrow = qbf + (size_t)(qw + ln) * QW + h * DQ;
    #pragma unroll
    for (int kb = 0; kb < 6; ++kb)
        aq[kb] = *(const short8*)(qrow + kb * 32 + quad * 8);

    const ushort* kfh = kf + (size_t)h * SS * 192;
    const ushort* vth2 = vt2 + ((size_t)h * 32 * 16) * 512 + lane * 8;

    const int key_s = tid >> 2;
    const int swp = ((tid & 3) ^ ((tid >> 3) & 3)) * 8;
    const ushort* kg = kfh + (size_t)(kstart + key_s) * 192 + swp;
    ushort* kdst = Kt + tid * 8;
    const int swq = (quad ^ ((ln >> 1) & 3)) * 8;

    f32x4 oacc[8];
    #pragma unroll
    for (int f = 0; f < 8; ++f) oacc[f] = (f32x4){0.f, 0.f, 0.f, 0.f};
    float mrow[4] = {-INFINITY, -INFINITY, -INFINITY, -INFINITY};
    float lrow[4] = {0.f, 0.f, 0.f, 0.f};

    // prologue: chunk c_lo -> registers
    short8 kreg[6];
    #pragma unroll
    for (int i = 0; i < 6; ++i) kreg[i] = *(const short8*)(kg + i * 32);
    kg += (size_t)64 * 192;

    for (int c = 0; c < nch; ++c) {
        const int k0 = kstart + (c << 6);
        // stage current chunk regs -> LDS (Kt free: guarded by loop-end barrier)
        #pragma unroll
        for (int i = 0; i < 6; ++i) *(short8*)(kdst + i * 2048) = kreg[i];
        // prefetch next chunk -> regs; stays in flight across barrier + compute
        if (c + 1 < nch) {
            #pragma unroll
            for (int i = 0; i < 6; ++i) kreg[i] = *(const short8*)(kg + i * 32);
            kg += (size_t)64 * 192;
        }
        asm volatile("s_waitcnt lgkmcnt(0)" ::: "memory");  // ds_writes done (NOT vmcnt)
        __builtin_amdgcn_s_barrier();
        asm volatile("" ::: "memory");

        if (k0 <= qw + 15) {
            const ushort* vfr = vth2 + (size_t)(k0 >> 6) * 16 * 512;
            short8 bv0[8];
            #pragma unroll
            for (int nb = 0; nb < 8; ++nb)
                bv0[nb] = *(const short8*)(vfr + (size_t)nb * 512);
            f32x4 s[4];
            #pragma unroll
            for (int ns = 0; ns < 4; ++ns) s[ns] = (f32x4){0.f, 0.f, 0.f, 0.f};
            #pragma unroll
            for (int ns = 0; ns < 4; ++ns)
                #pragma unroll
                for (int kb = 0; kb < 6; ++kb) {
                    short8 bk = *(const short8*)&Kt[(kb * 64 + ns * 16 + ln) * 32 + swq];
                    s[ns] = __builtin_amdgcn_mfma_f32_16x16x32_bf16(aq[kb], bk, s[ns], 0, 0, 0);
                }
            float pv[4][4], rmax[4];
            #pragma unroll
            for (int r = 0; r < 4; ++r) rmax[r] = -1e30f;
            #pragma unroll
            for (int ns = 0; ns < 4; ++ns)
                #pragma unroll
                for (int r = 0; r < 4; ++r) {
                    int key = k0 + ns * 16 + ln;
                    int qr = qw + quad * 4 + r;
                    float v = s[ns][r] * scale;
                    if (key > qr) v = -1e30f;
                    pv[ns][r] = v;
                    rmax[r] = fmaxf(rmax[r], v);
                }
            #pragma unroll
            for (int off = 8; off; off >>= 1)
                #pragma unroll
                for (int r = 0; r < 4; ++r)
                    rmax[r] = fmaxf(rmax[r], __shfl_xor(rmax[r], off));
            float alpha[4], psum[4];
            #pragma unroll
            for (int r = 0; r < 4; ++r) {
                float mnew = fmaxf(mrow[r], rmax[r]);
                alpha[r] = __expf(mrow[r] - mnew);
                mrow[r] = mnew;
            }
            #pragma unroll
            for (int ns = 0; ns < 4; ++ns)
                #pragma unroll
                for (int r = 0; r < 4; ++r)
                    pv[ns][r] = __expf(pv[ns][r] - mrow[r]);
            #pragma unroll
            for (int r = 0; r < 4; ++r)
                psum[r] = (pv[0][r] + pv[1][r]) + (pv[2][r] + pv[3][r]);
            #pragma unroll
            for (int off = 8; off; off >>= 1)
                #pragma unroll
                for (int r = 0; r < 4; ++r)
                    psum[r] += __shfl_xor(psum[r], off);
            #pragma unroll
            for (int r = 0; r < 4; ++r) lrow[r] = lrow[r] * alpha[r] + psum[r];
            #pragma unroll
            for (int f = 0; f < 8; ++f)
                #pragma unroll
                for (int r = 0; r < 4; ++r) oacc[f][r] *= alpha[r];
            #pragma unroll
            for (int ns = 0; ns < 4; ++ns)
                #pragma unroll
                for (int r = 0; r < 4; ++r)
                    Pt[wl][(quad * 4 + r) * PT_STRIDE + ns * 16 + ln] = f2b(pv[ns][r]);
            short8 bv1[8];
            #pragma unroll
            for (int nb = 0; nb < 8; ++nb)
                bv1[nb] = *(const short8*)(vfr + (size_t)(8 + nb) * 512);
            short8 pa0 = *(const short8*)&Pt[wl][ln * PT_STRIDE + quad * 8];
            short8 pa1 = *(const short8*)&Pt[wl][ln * PT_STRIDE + 32 + quad * 8];
            #pragma unroll
            for (int nb = 0; nb < 8; ++nb)
                oacc[nb] = __builtin_amdgcn_mfma_f32_16x16x32_bf16(pa0, bv0[nb], oacc[nb], 0, 0, 0);
            #pragma unroll
            for (int nb = 0; nb < 8; ++nb)
                oacc[nb] = __builtin_amdgcn_mfma_f32_16x16x32_bf16(pa1, bv1[nb], oacc[nb], 0, 0, 0);
        }
        // all waves done reading Kt before next iter's ds_write
        asm volatile("" ::: "memory");
        __builtin_amdgcn_s_barrier();
        asm volatile("" ::: "memory");
    }

    const size_t pbase = (((size_t)h * 32 + bq) * NSEG + seg) * 64;
    #pragma unroll
    for (int nb = 0; nb < 8; ++nb)
        #pragma unroll
        for (int r = 0; r < 4; ++r)
            opart[(pbase + wl * 16 + quad * 4 + r) * 128 + nb * 16 + ln] = f2b(oacc[nb][r]);
    if (ln == 0) {
        #pragma unroll
        for (int r = 0; r < 4; ++r) {
            ml[(pbase + wl * 16 + quad * 4 + r) * 2]     = mrow[r];
            ml[(pbase + wl * 16 + quad * 4 + r) * 2 + 1] = lrow[r];
        }
    }
}

// ---------------- merge partials -> obf ----------------
// seg s contributes to row-tile bq iff floor((s+1)*ctot/4) > floor(s*ctot/4)
// (must match attn_mfma2's chunk-split predicate exactly)
__global__ __launch_bounds__(256) void merge_attn(
    const ushort* __restrict__ opart, const float* __restrict__ ml,
    ushort* __restrict__ obf) {
    const int q = blockIdx.x;
    const int bq = q >> 6, row = q & 63;
    const int ctot = bq + 1;
    const int t = threadIdx.x;
    #pragma unroll
    for (int pp = 0; pp < 8; ++pp) {
        int idx = pp * 256 + t;            // 0..2047 = h*128 + d
        int h = idx >> 7, d = idx & 127;
        size_t rbase = (((size_t)h * 32 + bq) * NSEG) * 64 + row;  // + s*64
        float M = -1e30f;
        #pragma unroll
        for (int s = 0; s < NSEG; ++s) {
            if ((((s + 1) * ctot) >> 2) > ((s * ctot) >> 2))
                M = fmaxf(M, ml[(rbase + (size_t)s * 64) * 2]);
        }
        float L = 0.f, acc = 0.f;
        #pragma unroll
        for (int s = 0; s < NSEG; ++s) {
            if ((((s + 1) * ctot) >> 2) > ((s * ctot) >> 2)) {
                size_t ri = rbase + (size_t)s * 64;
                float w = __expf(ml[ri * 2] - M);
                L += w * ml[ri * 2 + 1];
                acc += w * b2f(opart[ri * 128 + d]);
            }
        }
        obf[(size_t)q * OW + h * DV + d] = f2b(acc / L);
    }
}

// ---------------- launch ----------------
extern "C" void kernel_launch(void* const* d_in, const int* in_sizes, int n_in,
                              void* d_out, int out_size, void* d_ws, size_t ws_size,
                              hipStream_t stream) {
    const void* x       = d_in[0];
    const void* w_q_a   = d_in[1];
    const void* q_a_ln  = d_in[2];
    const void* w_q_b   = d_in[3];
    const void* w_kv_a  = d_in[4];
    const void* kv_a_ln = d_in[5];
    const void* w_kv_b  = d_in[6];
    const void* w_out   = d_in[7];

    char* ws = (char*)d_ws;
    int*    flag  = (int*)ws;
    ushort* qbf   = (ushort*)(ws + 256);             // S*QW
    ushort* obf   = qbf   + (size_t)SS * QW;         // S*OW
    ushort* wqat  = obf   + (size_t)SS * OW;         // QLAT*EE  } contiguous ->
    ushort* wkvat = wqat  + (size_t)QLAT * EE;       // CKVW*EE  } merged Bt[2112][EE]
    ushort* wqbt  = wkvat + (size_t)CKVW * EE;       // QW*QLAT
    ushort* wkvbt = wqbt  + (size_t)QW * QLAT;       // KVW*KLAT
    ushort* woutt = wkvbt + (size_t)KVW * KLAT;      // EE*OW
    ushort* kf    = woutt + (size_t)EE * OW;         // HH*SS*192
    ushort* vt2   = kf    + (size_t)HH * SS * 192;   // HH*SS*DV (frag-ordered)
    float*  ml    = (float*)(vt2 + (size_t)HH * SS * DV);  // HH*32*NSEG*64*2 floats
    // overlay zone (all dead before attention writes opart):
    ushort* qac   = (ushort*)(ml + (size_t)HH * 32 * NSEG * 64 * 2);  // S*QAC
    ushort* xbf   = qac   + (size_t)SS * QAC;        // S*EE
    ushort* kvbf  = xbf   + (size_t)SS * EE;         // S*KVW
    ushort* kpebf = kvbf  + (size_t)SS * KVW;        // S*DR
    ushort* opart = qac;  // HH*32*NSEG*64*128 halfs <= overlay span (17.04M)

    detect_dtype<<<1, 1, 0, stream>>>((const unsigned int*)q_a_ln, flag);

    conv_x_bf<<<(SS * EE / 4 + 255) / 256, 256, 0, stream>>>(x, xbf, SS * EE, flag);
    transpose_bf<<<dim3(QLAT / 64, EE / 64), 256, 0, stream>>>(w_q_a, wqat, EE, QLAT, flag);
    transpose_bf<<<dim3(CKVW / 64, EE / 64), 256, 0, stream>>>(w_kv_a, wkvat, EE, CKVW, flag);
    transpose_bf<<<dim3(QW / 64, QLAT / 64), 256, 0, stream>>>(w_q_b, wqbt, QLAT, QW, flag);
    transpose_bf<<<dim3(KVW / 64, KLAT / 64), 256, 0, stream>>>(w_kv_b, wkvbt, KLAT, KVW, flag);
    transpose_bf<<<dim3(EE / 64, OW / 64), 256, 0, stream>>>(w_out, woutt, OW, EE, flag);

    // qac = x @ [w_q_a | w_kv_a]  (2048 x 2112, K=2048), merged, 544 blocks
    gemm_bf64<<<dim3((QAC + 127) / 128, SS / 64), 256, 0, stream>>>(
        xbf, wqat, qac, QAC, EE, EE, EE, QAC, 1, nullptr);

    rmsnorm_bf<<<SS, 256, 0, stream>>>(qac, q_a_ln, QLAT, QAC, flag);
    rmsnorm_bf<<<SS, 256, 0, stream>>>(qac + QLAT, kv_a_ln, KLAT, QAC, flag);

    // qbf = qa_norm @ w_q_b (2048x3072, K=1536), A = qac cols 0..1536
    gemm_bf<<<dim3(QW / 128, SS / 128), 256, 0, stream>>>(
        qac, wqbt, qbf, QW, QLAT, QAC, QLAT, QW, 1, nullptr);
    // kvbf = ckv_norm @ w_kv_b (2048x4096, K=512), A = qac cols 1536..2048
    gemm_bf<<<dim3(KVW / 128, SS / 128), 256, 0, stream>>>(
        qac + QLAT, wkvbt, kvbf, KVW, KLAT, QAC, KLAT, KVW, 1, nullptr);

    rope_q_bf<<<(SS * HH + 255) / 256, 256, 0, stream>>>(qbf);
    rope_k_bf<<<(SS + 63) / 64, 64, 0, stream>>>(qac + QLAT, kpebf, QAC);

    build_kf<<<SS * HH * 24 / 256, 256, 0, stream>>>(kvbf, kpebf, kf);
    build_vt2<<<dim3(SS / 64, HH), 256, 0, stream>>>(kvbf, vt2);

    attn_mfma2<<<dim3(NSEG, SS / 64, HH), 256, 0, stream>>>(qbf, kf, vt2, opart, ml);
    merge_attn<<<SS, 256, 0, stream>>>(opart, ml, obf);

    // out = o @ w_out (2048x2048, K=2048), 512 blocks via 64-tile
    gemm_bf64<<<dim3(EE / 128, SS / 64), 256, 0, stream>>>(
        obf, woutt, d_out, EE, OW, OW, OW, EE, 2, flag);
}

// Round 2
// 440.802 us; speedup vs baseline: 1.2694x; 1.2694x over previous
//
#include <hip/hip_runtime.h>
#include <hip/hip_bf16.h>
#include <math.h>

// Problem constants (fixed shapes)
#define SS   2048   // sequence length
#define EE   2048   // embed dim
#define HH   16     // heads
#define QLAT 1536   // q latent
#define KLAT 512    // kv latent
#define DN   128
#define DR   64
#define DV   128
#define DQ   192    // DN+DR
#define KVD  256    // DN+DV
#define CKVW 576    // KLAT+DR
#define QW   3072   // HH*DQ
#define KVW  4096   // HH*KVD
#define OW   2048   // HH*DV
#define QAC  2112   // QLAT + CKVW (merged a-proj output width)

#define NSEG 4      // key segments (flash-decoding split)
#define PT_STRIDE 72
#define KTSZ (6 * 64 * 32)   // one K-chunk in LDS (ushorts)

typedef __attribute__((ext_vector_type(8))) short short8;
typedef __attribute__((ext_vector_type(4))) float f32x4;

// ---------------- helpers ----------------
__global__ void detect_dtype(const unsigned int* __restrict__ lnw, int* flag) {
    *flag = (lnw[0] == 0x3F803F80u) ? 1 : 0;  // bf16 pair of 1.0 vs fp32 1.0
}

__device__ __forceinline__ float ld_in(const void* p, size_t i, int bf) {
    if (bf) return __bfloat162float(((const __hip_bfloat16*)p)[i]);
    return ((const float*)p)[i];
}

__device__ __forceinline__ ushort f2b(float v) {
    __hip_bfloat16 b = __float2bfloat16(v);
    return *(ushort*)&b;
}
__device__ __forceinline__ float b2f(ushort u) {
    __hip_bfloat16 b = *(__hip_bfloat16*)&u;
    return __bfloat162float(b);
}

// async global->LDS, 16 B per lane; LDS dst must be wave-uniform base + lane*16
__device__ __forceinline__ void async16(const ushort* g, ushort* l) {
    __builtin_amdgcn_global_load_lds(
        (const __attribute__((address_space(1))) void*)g,
        (__attribute__((address_space(3))) void*)l, 16, 0, 0);
}

// ---------------- input convert (x -> bf16) ----------------
__global__ __launch_bounds__(256) void conv_x_bf(
    const void* __restrict__ src, ushort* __restrict__ dst, int n, const int* flag) {
    const int bf = *flag;
    int i = (blockIdx.x * 256 + threadIdx.x) * 4;
    if (i >= n) return;
    ushort4 u;
    u.x = f2b(ld_in(src, i + 0, bf));
    u.y = f2b(ld_in(src, i + 1, bf));
    u.z = f2b(ld_in(src, i + 2, bf));
    u.w = f2b(ld_in(src, i + 3, bf));
    *(ushort4*)(dst + i) = u;
}

// ---------------- weight transpose+convert: in[R][C] -> out[C][R] bf16 ----------------
__global__ __launch_bounds__(256) void transpose_bf(
    const void* __restrict__ in, ushort* __restrict__ out,
    int R, int C, const int* flag) {
    const int bf = *flag;
    __shared__ ushort t[64][66];
    const int c0 = blockIdx.x * 64, r0 = blockIdx.y * 64;
    const int lane = threadIdx.x & 63, grp = threadIdx.x >> 6;
    #pragma unroll
    for (int p = 0; p < 16; ++p) {
        int r = p * 4 + grp;
        t[lane][r] = f2b(ld_in(in, (size_t)(r0 + r) * C + c0 + lane, bf));
    }
    __syncthreads();
    const int ro = (threadIdx.x & 31) * 2, co = threadIdx.x >> 5;
    #pragma unroll
    for (int p = 0; p < 8; ++p) {
        int c = p * 8 + co;
        ushort2 u = *(const ushort2*)&t[c][ro];
        *(ushort2*)&out[(size_t)(c0 + c) * R + r0 + ro] = u;
    }
}

// ---------------- bf16 MFMA GEMM 128x128: C[M][N] = A[M][K] @ Bt[N][K]^T ----------------
__global__ __launch_bounds__(256) void gemm_bf(
    const ushort* __restrict__ A, const ushort* __restrict__ Bt,
    void* __restrict__ C, int N, int K, int lda, int ldb, int ldc,
    int cmode, const int* __restrict__ cflag) {
    __shared__ ushort As[128 * 32];
    __shared__ ushort Bs[128 * 32];
    const int tid = threadIdx.x;
    const int bm = blockIdx.y * 128, bn = blockIdx.x * 128;
    const int lane = tid & 63, wv = tid >> 6;
    const int wm = (wv & 1) * 64, wn = (wv >> 1) * 64;
    const int ln = lane & 15, quad = lane >> 4;

    f32x4 acc[4][4];
    #pragma unroll
    for (int i = 0; i < 4; ++i)
        #pragma unroll
        for (int j = 0; j < 4; ++j) acc[i][j] = (f32x4){0.f, 0.f, 0.f, 0.f};

    const int srow = tid >> 2;
    const int spart = (((tid & 3) ^ ((tid >> 3) & 3))) * 8;  // swizzled source 16B part
    const ushort* Ag0 = A  + (size_t)(bm + srow) * lda + spart;
    const ushort* Ag1 = Ag0 + (size_t)64 * lda;
    const ushort* Bg0 = Bt + (size_t)(bn + srow) * ldb + spart;
    const ushort* Bg1 = Bg0 + (size_t)64 * ldb;
    ushort* Asl = As + tid * 8;
    ushort* Bsl = Bs + tid * 8;
    const bool bok0 = (bn + srow) < N;
    const bool bok1 = (bn + 64 + srow) < N;
    const int swq = (quad ^ ((ln >> 1) & 3)) * 8;  // swizzled read part

    for (int k0 = 0; k0 < K; k0 += 32) {
        async16(Ag0 + k0, Asl);
        async16(Ag1 + k0, Asl + 2048);
        if (bok0) async16(Bg0 + k0, Bsl);
        if (bok1) async16(Bg1 + k0, Bsl + 2048);
        __syncthreads();
        short8 af[4], bfr[4];
        #pragma unroll
        for (int t = 0; t < 4; ++t) {
            af[t]  = *(const short8*)&As[(wm + t * 16 + ln) * 32 + swq];
            bfr[t] = *(const short8*)&Bs[(wn + t * 16 + ln) * 32 + swq];
        }
        #pragma unroll
        for (int i = 0; i < 4; ++i)
            #pragma unroll
            for (int j = 0; j < 4; ++j)
                acc[i][j] = __builtin_amdgcn_mfma_f32_16x16x32_bf16(af[i], bfr[j], acc[i][j], 0, 0, 0);
        __syncthreads();
    }

    const int cbf = (cmode == 2) ? *cflag : cmode;
    #pragma unroll
    for (int i = 0; i < 4; ++i) {
        #pragma unroll
        for (int r = 0; r < 4; ++r) {
            const int m = bm + wm + i * 16 + quad * 4 + r;
            #pragma unroll
            for (int j = 0; j < 4; ++j) {
                const int n = bn + wn + j * 16 + ln;
                if (n < N) {
                    if (cbf) ((ushort*)C)[(size_t)m * ldc + n] = f2b(acc[i][j][r]);
                    else     ((float*)C)[(size_t)m * ldc + n] = acc[i][j][r];
                }
            }
        }
    }
}

// ---------------- bf16 MFMA GEMM 64x128 (small-grid variant) ----------------
__global__ __launch_bounds__(256) void gemm_bf64(
    const ushort* __restrict__ A, const ushort* __restrict__ Bt,
    void* __restrict__ C, int N, int K, int lda, int ldb, int ldc,
    int cmode, const int* __restrict__ cflag) {
    __shared__ ushort As[64 * 32];
    __shared__ ushort Bs[128 * 32];
    const int tid = threadIdx.x;
    const int bm = blockIdx.y * 64, bn = blockIdx.x * 128;
    const int lane = tid & 63, wv = tid >> 6;
    const int wm = (wv & 1) * 32, wn = (wv >> 1) * 64;
    const int ln = lane & 15, quad = lane >> 4;

    f32x4 acc[2][4];
    #pragma unroll
    for (int i = 0; i < 2; ++i)
        #pragma unroll
        for (int j = 0; j < 4; ++j) acc[i][j] = (f32x4){0.f, 0.f, 0.f, 0.f};

    const int srow = tid >> 2;
    const int spart = (((tid & 3) ^ ((tid >> 3) & 3))) * 8;
    const ushort* Ag0 = A  + (size_t)(bm + srow) * lda + spart;
    const ushort* Bg0 = Bt + (size_t)(bn + srow) * ldb + spart;
    const ushort* Bg1 = Bg0 + (size_t)64 * ldb;
    ushort* Asl = As + tid * 8;
    ushort* Bsl = Bs + tid * 8;
    const bool bok0 = (bn + srow) < N;
    const bool bok1 = (bn + 64 + srow) < N;
    const int swq = (quad ^ ((ln >> 1) & 3)) * 8;

    for (int k0 = 0; k0 < K; k0 += 32) {
        async16(Ag0 + k0, Asl);
        if (bok0) async16(Bg0 + k0, Bsl);
        if (bok1) async16(Bg1 + k0, Bsl + 2048);
        __syncthreads();
        short8 af[2], bfr[4];
        #pragma unroll
        for (int t = 0; t < 2; ++t)
            af[t] = *(const short8*)&As[(wm + t * 16 + ln) * 32 + swq];
        #pragma unroll
        for (int t = 0; t < 4; ++t)
            bfr[t] = *(const short8*)&Bs[(wn + t * 16 + ln) * 32 + swq];
        #pragma unroll
        for (int i = 0; i < 2; ++i)
            #pragma unroll
            for (int j = 0; j < 4; ++j)
                acc[i][j] = __builtin_amdgcn_mfma_f32_16x16x32_bf16(af[i], bfr[j], acc[i][j], 0, 0, 0);
        __syncthreads();
    }

    const int cbf = (cmode == 2) ? *cflag : cmode;
    #pragma unroll
    for (int i = 0; i < 2; ++i) {
        #pragma unroll
        for (int r = 0; r < 4; ++r) {
            const int m = bm + wm + i * 16 + quad * 4 + r;
            #pragma unroll
            for (int j = 0; j < 4; ++j) {
                const int n = bn + wn + j * 16 + ln;
                if (n < N) {
                    if (cbf) ((ushort*)C)[(size_t)m * ldc + n] = f2b(acc[i][j][r]);
                    else     ((float*)C)[(size_t)m * ldc + n] = acc[i][j][r];
                }
            }
        }
    }
}

// ---------------- RMSNorm bf16 in-place (fp32 math) ----------------
__global__ __launch_bounds__(256) void rmsnorm_bf(
    ushort* __restrict__ x, const void* __restrict__ w,
    int cols, int stride, const int* wflag) {
    const int wbf = *wflag;
    ushort* p = x + (size_t)blockIdx.x * stride;
    float ss = 0.f;
    for (int i = threadIdx.x; i < cols; i += 256) { float v = b2f(p[i]); ss += v * v; }
    #pragma unroll
    for (int off = 32; off; off >>= 1) ss += __shfl_xor(ss, off);
    __shared__ float red[4];
    const int wid = threadIdx.x >> 6, lane = threadIdx.x & 63;
    if (lane == 0) red[wid] = ss;
    __syncthreads();
    const float tot = red[0] + red[1] + red[2] + red[3];
    const float scale = rsqrtf(tot / (float)cols + 1e-6f);
    for (int i = threadIdx.x; i < cols; i += 256)
        p[i] = f2b(b2f(p[i]) * scale * ld_in(w, i, wbf));
}

// ---------------- RoPE (fp32 math on bf16 data) ----------------
__device__ __forceinline__ void rope64(const float* in, float t, float* out) {
    #pragma unroll
    for (int i = 0; i < 32; ++i) {
        float inv = powf(10000.0f, -(float)i / 32.0f);
        float sv, cv;
        sincosf(t * inv, &sv, &cv);
        float x0 = in[2 * i], x1 = in[2 * i + 1];
        out[i]      = x0 * cv - x1 * sv;
        out[i + 32] = x1 * cv + x0 * sv;
    }
}

__global__ void rope_q_bf(ushort* __restrict__ q) {
    int idx = blockIdx.x * blockDim.x + threadIdx.x;
    if (idx >= SS * HH) return;
    int s = idx >> 4, h = idx & 15;
    ushort* p = q + (size_t)s * QW + h * DQ + DN;
    float buf[DR], out[DR];
    #pragma unroll
    for (int i = 0; i < DR; ++i) buf[i] = b2f(p[i]);
    rope64(buf, (float)s, out);
    #pragma unroll
    for (int i = 0; i < DR; ++i) p[i] = f2b(out[i]);
}

__global__ void rope_k_bf(const ushort* __restrict__ ckv, ushort* __restrict__ kpe,
                          int stride) {
    int s = blockIdx.x * blockDim.x + threadIdx.x;
    if (s >= SS) return;
    const ushort* p = ckv + (size_t)s * stride + KLAT;
    float buf[DR], out[DR];
    #pragma unroll
    for (int i = 0; i < DR; ++i) buf[i] = b2f(p[i]);
    rope64(buf, (float)s, out);
    ushort* dp = kpe + (size_t)s * DR;
    #pragma unroll
    for (int i = 0; i < DR; ++i) dp[i] = f2b(out[i]);
}

// ---------------- build head-major K-full: kf[h][s][192] ----------------
__global__ __launch_bounds__(256) void build_kf(
    const ushort* __restrict__ kv, const ushort* __restrict__ kpe,
    ushort* __restrict__ kf) {
    int idx = blockIdx.x * 256 + threadIdx.x;       // SS*HH*24 items
    int part = idx % 24;
    int rest = idx / 24;
    int h = rest & 15, s = rest >> 4;
    short8 v;
    if (part < 16) v = *(const short8*)(kv + (size_t)s * KVW + h * KVD + part * 8);
    else           v = *(const short8*)(kpe + (size_t)s * DR + (part - 16) * 8);
    *(short8*)(kf + ((size_t)h * SS + s) * 192 + part * 8) = v;
}

// ---------------- build frag-ordered V: vt2[h][ck][idx2=kb2*8+nb][lane][8] ----------------
__global__ __launch_bounds__(256) void build_vt2(
    const ushort* __restrict__ kv, ushort* __restrict__ vt2) {
    __shared__ ushort Vl[64 * 136];
    const int ck = blockIdx.x, h = blockIdx.y;
    const int tid = threadIdx.x;
    const int lane = tid & 63, wv = tid >> 6;
    #pragma unroll
    for (int rr = 0; rr < 4; ++rr) {
        int n = rr * 256 + tid;
        int key = n >> 4, part = n & 15;
        short8 v = *(const short8*)(kv + (size_t)(ck * 64 + key) * KVW + h * KVD + DN + part * 8);
        *(short8*)&Vl[key * 136 + part * 8] = v;
    }
    __syncthreads();
    const int ln = lane & 15, quad = lane >> 4;
    ushort* dst = vt2 + (((size_t)h * 32 + ck) * 16) * 512;
    #pragma unroll
    for (int w = 0; w < 4; ++w) {
        int idx2 = wv * 4 + w;
        int kb2 = idx2 >> 3, nb = idx2 & 7;
        short8 v;
        #pragma unroll
        for (int j = 0; j < 8; ++j)
            ((ushort*)&v)[j] = Vl[(kb2 * 32 + quad * 8 + j) * 136 + nb * 16 + ln];
        *(short8*)(dst + (size_t)idx2 * 512 + lane * 8) = v;
    }
}

// ---------------- split-K MFMA flash attention ----------------
// v3: balanced contiguous chunk split (kept from v2; occupancy 19->25%) +
// LDS double-buffered K staging via global_load_lds (reverts v2's reg-staging,
// which spilled to scratch: +260MB FETCH/WRITE each).
// Pipeline: prologue stages chunk 0 into buf0; each iter: vmcnt(0) [drains the
// current buffer's loads, issued one full compute-phase earlier] -> barrier ->
// issue chunk c+1 into buf^1 -> compute chunk c. One barrier/iter is race-free:
// buf[(c+1)&1] was last read in compute(c-1), which precedes barrier(c) in
// every wave's program order.
__global__ __launch_bounds__(256, 2) void attn_mfma2(
    const ushort* __restrict__ qbf, const ushort* __restrict__ kf,
    const ushort* __restrict__ vt2, ushort* __restrict__ opart,
    float* __restrict__ ml) {
    const int seg = blockIdx.x, bq = 31 - blockIdx.y, h = blockIdx.z;
    const int ctot = bq + 1;
    const int c_lo = (seg * ctot) >> 2;
    const int nch = (((seg + 1) * ctot) >> 2) - c_lo;
    if (nch <= 0) return;

    __shared__ ushort Kt[2 * KTSZ];              // 2 x 24576 B
    __shared__ ushort Pt[4][16 * PT_STRIDE];     // 9216 B

    const int tid = threadIdx.x, lane = tid & 63, wl = tid >> 6;
    const int ln = lane & 15, quad = lane >> 4;
    const int qw = bq * 64 + wl * 16;
    const int kstart = c_lo << 6;
    const float scale = 0.07216878364870322f;  // 1/sqrt(192)

    short8 aq[6];
    const ushort* qrow = qbf + (size_t)(qw + ln) * QW + h * DQ;
    #pragma unroll
    for (int kb = 0; kb < 6; ++kb)
        aq[kb] = *(const short8*)(qrow + kb * 32 + quad * 8);

    const ushort* kfh = kf + (size_t)h * SS * 192;
    const ushort* vth2 = vt2 + ((size_t)h * 32 * 16) * 512 + lane * 8;

    const int key_s = tid >> 2;
    const int swp = ((tid & 3) ^ ((tid >> 3) & 3)) * 8;
    const ushort* kg = kfh + (size_t)(kstart + key_s) * 192 + swp;
    const int swq = (quad ^ ((ln >> 1) & 3)) * 8;

    f32x4 oacc[8];
    #pragma unroll
    for (int f = 0; f < 8; ++f) oacc[f] = (f32x4){0.f, 0.f, 0.f, 0.f};
    float mrow[4] = {-INFINITY, -INFINITY, -INFINITY, -INFINITY};
    float lrow[4] = {0.f, 0.f, 0.f, 0.f};

    // prologue: stage chunk c_lo into buffer 0
    {
        ushort* kd = Kt + tid * 8;
        #pragma unroll
        for (int i = 0; i < 6; ++i)
            async16(kg + i * 32, kd + i * 2048);
        kg += (size_t)64 * 192;
    }

    for (int c = 0; c < nch; ++c) {
        const int k0 = kstart + (c << 6);
        // wait for own loads targeting buf[c&1] (issued one compute-phase ago)
        asm volatile("s_waitcnt vmcnt(0)" ::: "memory");
        __builtin_amdgcn_s_barrier();
        asm volatile("" ::: "memory");
        // prefetch chunk c+1 into the other buffer; stays in flight across compute
        if (c + 1 < nch) {
            ushort* kd = Kt + ((c + 1) & 1) * KTSZ + tid * 8;
            #pragma unroll
            for (int i = 0; i < 6; ++i)
                async16(kg + i * 32, kd + i * 2048);
            kg += (size_t)64 * 192;
        }
        const ushort* Kcur = Kt + (c & 1) * KTSZ;

        const ushort* vfr = vth2 + (size_t)(k0 >> 6) * 16 * 512;
        short8 bv0[8];
        #pragma unroll
        for (int nb = 0; nb < 8; ++nb)
            bv0[nb] = *(const short8*)(vfr + (size_t)nb * 512);
        f32x4 s[4];
        #pragma unroll
        for (int ns = 0; ns < 4; ++ns) s[ns] = (f32x4){0.f, 0.f, 0.f, 0.f};
        __builtin_amdgcn_s_setprio(1);
        #pragma unroll
        for (int ns = 0; ns < 4; ++ns)
            #pragma unroll
            for (int kb = 0; kb < 6; ++kb) {
                short8 bk = *(const short8*)&Kcur[(kb * 64 + ns * 16 + ln) * 32 + swq];
                s[ns] = __builtin_amdgcn_mfma_f32_16x16x32_bf16(aq[kb], bk, s[ns], 0, 0, 0);
            }
        __builtin_amdgcn_s_setprio(0);
        float pv[4][4], rmax[4];
        #pragma unroll
        for (int r = 0; r < 4; ++r) rmax[r] = -1e30f;
        #pragma unroll
        for (int ns = 0; ns < 4; ++ns)
            #pragma unroll
            for (int r = 0; r < 4; ++r) {
                int key = k0 + ns * 16 + ln;
                int qr = qw + quad * 4 + r;
                float v = s[ns][r] * scale;
                if (key > qr) v = -1e30f;
                pv[ns][r] = v;
                rmax[r] = fmaxf(rmax[r], v);
            }
        #pragma unroll
        for (int off = 8; off; off >>= 1)
            #pragma unroll
            for (int r = 0; r < 4; ++r)
                rmax[r] = fmaxf(rmax[r], __shfl_xor(rmax[r], off));
        float alpha[4], psum[4];
        #pragma unroll
        for (int r = 0; r < 4; ++r) {
            float mnew = fmaxf(mrow[r], rmax[r]);
            alpha[r] = __expf(mrow[r] - mnew);
            mrow[r] = mnew;
        }
        #pragma unroll
        for (int ns = 0; ns < 4; ++ns)
            #pragma unroll
            for (int r = 0; r < 4; ++r)
                pv[ns][r] = __expf(pv[ns][r] - mrow[r]);
        #pragma unroll
        for (int r = 0; r < 4; ++r)
            psum[r] = (pv[0][r] + pv[1][r]) + (pv[2][r] + pv[3][r]);
        #pragma unroll
        for (int off = 8; off; off >>= 1)
            #pragma unroll
            for (int r = 0; r < 4; ++r)
                psum[r] += __shfl_xor(psum[r], off);
        #pragma unroll
        for (int r = 0; r < 4; ++r) lrow[r] = lrow[r] * alpha[r] + psum[r];
        #pragma unroll
        for (int f = 0; f < 8; ++f)
            #pragma unroll
            for (int r = 0; r < 4; ++r) oacc[f][r] *= alpha[r];
        #pragma unroll
        for (int ns = 0; ns < 4; ++ns)
            #pragma unroll
            for (int r = 0; r < 4; ++r)
                Pt[wl][(quad * 4 + r) * PT_STRIDE + ns * 16 + ln] = f2b(pv[ns][r]);
        short8 bv1[8];
        #pragma unroll
        for (int nb = 0; nb < 8; ++nb)
            bv1[nb] = *(const short8*)(vfr + (size_t)(8 + nb) * 512);
        short8 pa0 = *(const short8*)&Pt[wl][ln * PT_STRIDE + quad * 8];
        short8 pa1 = *(const short8*)&Pt[wl][ln * PT_STRIDE + 32 + quad * 8];
        __builtin_amdgcn_s_setprio(1);
        #pragma unroll
        for (int nb = 0; nb < 8; ++nb)
            oacc[nb] = __builtin_amdgcn_mfma_f32_16x16x32_bf16(pa0, bv0[nb], oacc[nb], 0, 0, 0);
        #pragma unroll
        for (int nb = 0; nb < 8; ++nb)
            oacc[nb] = __builtin_amdgcn_mfma_f32_16x16x32_bf16(pa1, bv1[nb], oacc[nb], 0, 0, 0);
        __builtin_amdgcn_s_setprio(0);
    }

    const size_t pbase = (((size_t)h * 32 + bq) * NSEG + seg) * 64;
    #pragma unroll
    for (int nb = 0; nb < 8; ++nb)
        #pragma unroll
        for (int r = 0; r < 4; ++r)
            opart[(pbase + wl * 16 + quad * 4 + r) * 128 + nb * 16 + ln] = f2b(oacc[nb][r]);
    if (ln == 0) {
        #pragma unroll
        for (int r = 0; r < 4; ++r) {
            ml[(pbase + wl * 16 + quad * 4 + r) * 2]     = mrow[r];
            ml[(pbase + wl * 16 + quad * 4 + r) * 2 + 1] = lrow[r];
        }
    }
}

// ---------------- merge partials -> obf ----------------
// seg s contributes to row-tile bq iff floor((s+1)*ctot/4) > floor(s*ctot/4)
// (must match attn_mfma2's chunk-split predicate exactly)
__global__ __launch_bounds__(256) void merge_attn(
    const ushort* __restrict__ opart, const float* __restrict__ ml,
    ushort* __restrict__ obf) {
    const int q = blockIdx.x;
    const int bq = q >> 6, row = q & 63;
    const int ctot = bq + 1;
    const int t = threadIdx.x;
    #pragma unroll
    for (int pp = 0; pp < 8; ++pp) {
        int idx = pp * 256 + t;            // 0..2047 = h*128 + d
        int h = idx >> 7, d = idx & 127;
        size_t rbase = (((size_t)h * 32 + bq) * NSEG) * 64 + row;  // + s*64
        float M = -1e30f;
        #pragma unroll
        for (int s = 0; s < NSEG; ++s) {
            if ((((s + 1) * ctot) >> 2) > ((s * ctot) >> 2))
                M = fmaxf(M, ml[(rbase + (size_t)s * 64) * 2]);
        }
        float L = 0.f, acc = 0.f;
        #pragma unroll
        for (int s = 0; s < NSEG; ++s) {
            if ((((s + 1) * ctot) >> 2) > ((s * ctot) >> 2)) {
                size_t ri = rbase + (size_t)s * 64;
                float w = __expf(ml[ri * 2] - M);
                L += w * ml[ri * 2 + 1];
                acc += w * b2f(opart[ri * 128 + d]);
            }
        }
        obf[(size_t)q * OW + h * DV + d] = f2b(acc / L);
    }
}

// ---------------- launch ----------------
extern "C" void kernel_launch(void* const* d_in, const int* in_sizes, int n_in,
                              void* d_out, int out_size, void* d_ws, size_t ws_size,
                              hipStream_t stream) {
    const void* x       = d_in[0];
    const void* w_q_a   = d_in[1];
    const void* q_a_ln  = d_in[2];
    const void* w_q_b   = d_in[3];
    const void* w_kv_a  = d_in[4];
    const void* kv_a_ln = d_in[5];
    const void* w_kv_b  = d_in[6];
    const void* w_out   = d_in[7];

    char* ws = (char*)d_ws;
    int*    flag  = (int*)ws;
    ushort* qbf   = (ushort*)(ws + 256);             // S*QW
    ushort* obf   = qbf   + (size_t)SS * QW;         // S*OW
    ushort* wqat  = obf   + (size_t)SS * OW;         // QLAT*EE  } contiguous ->
    ushort* wkvat = wqat  + (size_t)QLAT * EE;       // CKVW*EE  } merged Bt[2112][EE]
    ushort* wqbt  = wkvat + (size_t)CKVW * EE;       // QW*QLAT
    ushort* wkvbt = wqbt  + (size_t)QW * QLAT;       // KVW*KLAT
    ushort* woutt = wkvbt + (size_t)KVW * KLAT;      // EE*OW
    ushort* kf    = woutt + (size_t)EE * OW;         // HH*SS*192
    ushort* vt2   = kf    + (size_t)HH * SS * 192;   // HH*SS*DV (frag-ordered)
    float*  ml    = (float*)(vt2 + (size_t)HH * SS * DV);  // HH*32*NSEG*64*2 floats
    // overlay zone (all dead before attention writes opart):
    ushort* qac   = (ushort*)(ml + (size_t)HH * 32 * NSEG * 64 * 2);  // S*QAC
    ushort* xbf   = qac   + (size_t)SS * QAC;        // S*EE
    ushort* kvbf  = xbf   + (size_t)SS * EE;         // S*KVW
    ushort* kpebf = kvbf  + (size_t)SS * KVW;        // S*DR
    ushort* opart = qac;  // HH*32*NSEG*64*128 halfs <= overlay span (17.04M)

    detect_dtype<<<1, 1, 0, stream>>>((const unsigned int*)q_a_ln, flag);

    conv_x_bf<<<(SS * EE / 4 + 255) / 256, 256, 0, stream>>>(x, xbf, SS * EE, flag);
    transpose_bf<<<dim3(QLAT / 64, EE / 64), 256, 0, stream>>>(w_q_a, wqat, EE, QLAT, flag);
    transpose_bf<<<dim3(CKVW / 64, EE / 64), 256, 0, stream>>>(w_kv_a, wkvat, EE, CKVW, flag);
    transpose_bf<<<dim3(QW / 64, QLAT / 64), 256, 0, stream>>>(w_q_b, wqbt, QLAT, QW, flag);
    transpose_bf<<<dim3(KVW / 64, KLAT / 64), 256, 0, stream>>>(w_kv_b, wkvbt, KLAT, KVW, flag);
    transpose_bf<<<dim3(EE / 64, OW / 64), 256, 0, stream>>>(w_out, woutt, OW, EE, flag);

    // qac = x @ [w_q_a | w_kv_a]  (2048 x 2112, K=2048), merged, 544 blocks
    gemm_bf64<<<dim3((QAC + 127) / 128, SS / 64), 256, 0, stream>>>(
        xbf, wqat, qac, QAC, EE, EE, EE, QAC, 1, nullptr);

    rmsnorm_bf<<<SS, 256, 0, stream>>>(qac, q_a_ln, QLAT, QAC, flag);
    rmsnorm_bf<<<SS, 256, 0, stream>>>(qac + QLAT, kv_a_ln, KLAT, QAC, flag);

    // qbf = qa_norm @ w_q_b (2048x3072, K=1536), A = qac cols 0..1536
    gemm_bf<<<dim3(QW / 128, SS / 128), 256, 0, stream>>>(
        qac, wqbt, qbf, QW, QLAT, QAC, QLAT, QW, 1, nullptr);
    // kvbf = ckv_norm @ w_kv_b (2048x4096, K=512), A = qac cols 1536..2048
    gemm_bf<<<dim3(KVW / 128, SS / 128), 256, 0, stream>>>(
        qac + QLAT, wkvbt, kvbf, KVW, KLAT, QAC, KLAT, KVW, 1, nullptr);

    rope_q_bf<<<(SS * HH + 255) / 256, 256, 0, stream>>>(qbf);
    rope_k_bf<<<(SS + 63) / 64, 64, 0, stream>>>(qac + QLAT, kpebf, QAC);

    build_kf<<<SS * HH * 24 / 256, 256, 0, stream>>>(kvbf, kpebf, kf);
    build_vt2<<<dim3(SS / 64, HH), 256, 0, stream>>>(kvbf, vt2);

    attn_mfma2<<<dim3(NSEG, SS / 64, HH), 256, 0, stream>>>(qbf, kf, vt2, opart, ml);
    merge_attn<<<SS, 256, 0, stream>>>(opart, ml, obf);

    // out = o @ w_out (2048x2048, K=2048), 512 blocks via 64-tile
    gemm_bf64<<<dim3(EE / 128, SS / 64), 256, 0, stream>>>(
        obf, woutt, d_out, EE, OW, OW, OW, EE, 2, flag);
}

// Round 3
// 417.346 us; speedup vs baseline: 1.3407x; 1.0562x over previous
//
#include <hip/hip_runtime.h>
#include <hip/hip_bf16.h>
#include <math.h>

// Problem constants (fixed shapes)
#define SS   2048   // sequence length
#define EE   2048   // embed dim
#define HH   16     // heads
#define QLAT 1536   // q latent
#define KLAT 512    // kv latent
#define DN   128
#define DR   64
#define DV   128
#define DQ   192    // DN+DR
#define KVD  256    // DN+DV
#define CKVW 576    // KLAT+DR
#define QW   3072   // HH*DQ
#define KVW  4096   // HH*KVD
#define OW   2048   // HH*DV
#define QAC  2112   // QLAT + CKVW (merged a-proj output width)

#define NSEG 4      // key segments (flash-decoding split)
#define PT_STRIDE 72
#define KTSZ (6 * 64 * 32)   // one K-chunk in LDS (ushorts)

typedef __attribute__((ext_vector_type(8))) short short8;
typedef __attribute__((ext_vector_type(4))) float f32x4;

// ---------------- helpers ----------------
__global__ void detect_dtype(const unsigned int* __restrict__ lnw, int* flag) {
    *flag = (lnw[0] == 0x3F803F80u) ? 1 : 0;  // bf16 pair of 1.0 vs fp32 1.0
}

__device__ __forceinline__ float ld_in(const void* p, size_t i, int bf) {
    if (bf) return __bfloat162float(((const __hip_bfloat16*)p)[i]);
    return ((const float*)p)[i];
}

__device__ __forceinline__ ushort f2b(float v) {
    __hip_bfloat16 b = __float2bfloat16(v);
    return *(ushort*)&b;
}
__device__ __forceinline__ float b2f(ushort u) {
    __hip_bfloat16 b = *(__hip_bfloat16*)&u;
    return __bfloat162float(b);
}

// async global->LDS, 16 B per lane; LDS dst must be wave-uniform base + lane*16
__device__ __forceinline__ void async16(const ushort* g, ushort* l) {
    __builtin_amdgcn_global_load_lds(
        (const __attribute__((address_space(1))) void*)g,
        (__attribute__((address_space(3))) void*)l, 16, 0, 0);
}

// ---------------- input convert (x -> bf16) ----------------
__global__ __launch_bounds__(256) void conv_x_bf(
    const void* __restrict__ src, ushort* __restrict__ dst, int n, const int* flag) {
    const int bf = *flag;
    int i = (blockIdx.x * 256 + threadIdx.x) * 4;
    if (i >= n) return;
    ushort4 u;
    u.x = f2b(ld_in(src, i + 0, bf));
    u.y = f2b(ld_in(src, i + 1, bf));
    u.z = f2b(ld_in(src, i + 2, bf));
    u.w = f2b(ld_in(src, i + 3, bf));
    *(ushort4*)(dst + i) = u;
}

// ---------------- batched weight transpose+convert: in[R][C] -> out[C][R] bf16 ----
// One launch for all 5 weight matrices; blockIdx.z selects. Out-of-range
// tiles early-exit. 64x64 tiles, LDS stride 66 (conflict-free).
__global__ __launch_bounds__(256) void transpose5_bf(
    const void* __restrict__ s0, const void* __restrict__ s1,
    const void* __restrict__ s2, const void* __restrict__ s3,
    const void* __restrict__ s4,
    ushort* __restrict__ d0, ushort* __restrict__ d1, ushort* __restrict__ d2,
    ushort* __restrict__ d3, ushort* __restrict__ d4,
    const int* flag) {
    const int z = blockIdx.z;
    const void* in; ushort* out; int R, C;
    switch (z) {
        case 0:  in = s0; out = d0; R = EE;   C = QLAT; break;  // w_q_a
        case 1:  in = s1; out = d1; R = EE;   C = CKVW; break;  // w_kv_a
        case 2:  in = s2; out = d2; R = QLAT; C = QW;   break;  // w_q_b
        case 3:  in = s3; out = d3; R = KLAT; C = KVW;  break;  // w_kv_b
        default: in = s4; out = d4; R = OW;   C = EE;   break;  // w_out
    }
    const int c0 = blockIdx.x * 64, r0 = blockIdx.y * 64;
    if (c0 >= C || r0 >= R) return;
    const int bf = *flag;
    __shared__ ushort t[64][66];
    const int lane = threadIdx.x & 63, grp = threadIdx.x >> 6;
    #pragma unroll
    for (int p = 0; p < 16; ++p) {
        int r = p * 4 + grp;
        t[lane][r] = f2b(ld_in(in, (size_t)(r0 + r) * C + c0 + lane, bf));
    }
    __syncthreads();
    const int ro = (threadIdx.x & 31) * 2, co = threadIdx.x >> 5;
    #pragma unroll
    for (int p = 0; p < 8; ++p) {
        int c = p * 8 + co;
        ushort2 u = *(const ushort2*)&t[c][ro];
        *(ushort2*)&out[(size_t)(c0 + c) * R + r0 + ro] = u;
    }
}

// ---------------- bf16 MFMA GEMM 128x128, LDS double-buffered ----------------
// C[M][N] = A[M][K] @ Bt[N][K]^T. XOR-swizzled LDS (16B part p of row r at
// p^((r>>1)&3)). Pipeline (proven in attn v3): prologue stages step 0 into
// buf0; each iter: vmcnt(0) [drains loads issued one compute-phase ago] ->
// barrier -> issue step c+1 into buf^1 -> compute step c. Single barrier/iter
// is race-free: buf[(c+1)&1] was last read in compute(c-1), which precedes
// barrier(c) in every wave's program order (ds_reads lgkmcnt-drained before
// the MFMAs that consume them).
__global__ __launch_bounds__(256) void gemm_bf(
    const ushort* __restrict__ A, const ushort* __restrict__ Bt,
    void* __restrict__ C, int N, int K, int lda, int ldb, int ldc,
    int cmode, const int* __restrict__ cflag) {
    __shared__ ushort As[2][128 * 32];
    __shared__ ushort Bs[2][128 * 32];
    const int tid = threadIdx.x;
    const int bm = blockIdx.y * 128, bn = blockIdx.x * 128;
    const int lane = tid & 63, wv = tid >> 6;
    const int wm = (wv & 1) * 64, wn = (wv >> 1) * 64;
    const int ln = lane & 15, quad = lane >> 4;

    f32x4 acc[4][4];
    #pragma unroll
    for (int i = 0; i < 4; ++i)
        #pragma unroll
        for (int j = 0; j < 4; ++j) acc[i][j] = (f32x4){0.f, 0.f, 0.f, 0.f};

    const int srow = tid >> 2;
    const int spart = (((tid & 3) ^ ((tid >> 3) & 3))) * 8;  // swizzled source 16B part
    const ushort* Ag0 = A  + (size_t)(bm + srow) * lda + spart;
    const ushort* Ag1 = Ag0 + (size_t)64 * lda;
    const ushort* Bg0 = Bt + (size_t)(bn + srow) * ldb + spart;
    const ushort* Bg1 = Bg0 + (size_t)64 * ldb;
    const bool bok0 = (bn + srow) < N;
    const bool bok1 = (bn + 64 + srow) < N;
    const int swq = (quad ^ ((ln >> 1) & 3)) * 8;  // swizzled read part
    const int nsteps = K >> 5;

    // prologue: stage step 0 into buffer 0
    {
        ushort* Asl = As[0] + tid * 8;
        ushort* Bsl = Bs[0] + tid * 8;
        async16(Ag0, Asl);
        async16(Ag1, Asl + 2048);
        if (bok0) async16(Bg0, Bsl);
        if (bok1) async16(Bg1, Bsl + 2048);
    }

    for (int c = 0; c < nsteps; ++c) {
        asm volatile("s_waitcnt vmcnt(0)" ::: "memory");
        __builtin_amdgcn_s_barrier();
        asm volatile("" ::: "memory");
        if (c + 1 < nsteps) {
            const int k1 = (c + 1) << 5;
            const int nb = (c + 1) & 1;
            ushort* Asl = As[nb] + tid * 8;
            ushort* Bsl = Bs[nb] + tid * 8;
            async16(Ag0 + k1, Asl);
            async16(Ag1 + k1, Asl + 2048);
            if (bok0) async16(Bg0 + k1, Bsl);
            if (bok1) async16(Bg1 + k1, Bsl + 2048);
        }
        const ushort* Ac = As[c & 1];
        const ushort* Bc = Bs[c & 1];
        short8 af[4], bfr[4];
        #pragma unroll
        for (int t = 0; t < 4; ++t) {
            af[t]  = *(const short8*)&Ac[(wm + t * 16 + ln) * 32 + swq];
            bfr[t] = *(const short8*)&Bc[(wn + t * 16 + ln) * 32 + swq];
        }
        __builtin_amdgcn_s_setprio(1);
        #pragma unroll
        for (int i = 0; i < 4; ++i)
            #pragma unroll
            for (int j = 0; j < 4; ++j)
                acc[i][j] = __builtin_amdgcn_mfma_f32_16x16x32_bf16(af[i], bfr[j], acc[i][j], 0, 0, 0);
        __builtin_amdgcn_s_setprio(0);
    }

    const int cbf = (cmode == 2) ? *cflag : cmode;
    #pragma unroll
    for (int i = 0; i < 4; ++i) {
        #pragma unroll
        for (int r = 0; r < 4; ++r) {
            const int m = bm + wm + i * 16 + quad * 4 + r;
            #pragma unroll
            for (int j = 0; j < 4; ++j) {
                const int n = bn + wn + j * 16 + ln;
                if (n < N) {
                    if (cbf) ((ushort*)C)[(size_t)m * ldc + n] = f2b(acc[i][j][r]);
                    else     ((float*)C)[(size_t)m * ldc + n] = acc[i][j][r];
                }
            }
        }
    }
}

// ---------------- bf16 MFMA GEMM 64x128, LDS double-buffered ----------------
__global__ __launch_bounds__(256) void gemm_bf64(
    const ushort* __restrict__ A, const ushort* __restrict__ Bt,
    void* __restrict__ C, int N, int K, int lda, int ldb, int ldc,
    int cmode, const int* __restrict__ cflag) {
    __shared__ ushort As[2][64 * 32];
    __shared__ ushort Bs[2][128 * 32];
    const int tid = threadIdx.x;
    const int bm = blockIdx.y * 64, bn = blockIdx.x * 128;
    const int lane = tid & 63, wv = tid >> 6;
    const int wm = (wv & 1) * 32, wn = (wv >> 1) * 64;
    const int ln = lane & 15, quad = lane >> 4;

    f32x4 acc[2][4];
    #pragma unroll
    for (int i = 0; i < 2; ++i)
        #pragma unroll
        for (int j = 0; j < 4; ++j) acc[i][j] = (f32x4){0.f, 0.f, 0.f, 0.f};

    const int srow = tid >> 2;
    const int spart = (((tid & 3) ^ ((tid >> 3) & 3))) * 8;
    const ushort* Ag0 = A  + (size_t)(bm + srow) * lda + spart;
    const ushort* Bg0 = Bt + (size_t)(bn + srow) * ldb + spart;
    const ushort* Bg1 = Bg0 + (size_t)64 * ldb;
    const bool bok0 = (bn + srow) < N;
    const bool bok1 = (bn + 64 + srow) < N;
    const int swq = (quad ^ ((ln >> 1) & 3)) * 8;
    const int nsteps = K >> 5;

    // prologue: stage step 0 into buffer 0
    {
        ushort* Asl = As[0] + tid * 8;
        ushort* Bsl = Bs[0] + tid * 8;
        async16(Ag0, Asl);
        if (bok0) async16(Bg0, Bsl);
        if (bok1) async16(Bg1, Bsl + 2048);
    }

    for (int c = 0; c < nsteps; ++c) {
        asm volatile("s_waitcnt vmcnt(0)" ::: "memory");
        __builtin_amdgcn_s_barrier();
        asm volatile("" ::: "memory");
        if (c + 1 < nsteps) {
            const int k1 = (c + 1) << 5;
            const int nb = (c + 1) & 1;
            ushort* Asl = As[nb] + tid * 8;
            ushort* Bsl = Bs[nb] + tid * 8;
            async16(Ag0 + k1, Asl);
            if (bok0) async16(Bg0 + k1, Bsl);
            if (bok1) async16(Bg1 + k1, Bsl + 2048);
        }
        const ushort* Ac = As[c & 1];
        const ushort* Bc = Bs[c & 1];
        short8 af[2], bfr[4];
        #pragma unroll
        for (int t = 0; t < 2; ++t)
            af[t] = *(const short8*)&Ac[(wm + t * 16 + ln) * 32 + swq];
        #pragma unroll
        for (int t = 0; t < 4; ++t)
            bfr[t] = *(const short8*)&Bc[(wn + t * 16 + ln) * 32 + swq];
        __builtin_amdgcn_s_setprio(1);
        #pragma unroll
        for (int i = 0; i < 2; ++i)
            #pragma unroll
            for (int j = 0; j < 4; ++j)
                acc[i][j] = __builtin_amdgcn_mfma_f32_16x16x32_bf16(af[i], bfr[j], acc[i][j], 0, 0, 0);
        __builtin_amdgcn_s_setprio(0);
    }

    const int cbf = (cmode == 2) ? *cflag : cmode;
    #pragma unroll
    for (int i = 0; i < 2; ++i) {
        #pragma unroll
        for (int r = 0; r < 4; ++r) {
            const int m = bm + wm + i * 16 + quad * 4 + r;
            #pragma unroll
            for (int j = 0; j < 4; ++j) {
                const int n = bn + wn + j * 16 + ln;
                if (n < N) {
                    if (cbf) ((ushort*)C)[(size_t)m * ldc + n] = f2b(acc[i][j][r]);
                    else     ((float*)C)[(size_t)m * ldc + n] = acc[i][j][r];
                }
            }
        }
    }
}

// ---------------- RMSNorm bf16 in-place (fp32 math), both norms fused ------
// blockIdx.y: 0 -> q latent (cols QLAT, off 0, w=wq); 1 -> kv latent.
__global__ __launch_bounds__(256) void rmsnorm2_bf(
    ushort* __restrict__ x, const void* __restrict__ wq,
    const void* __restrict__ wkv, const int* wflag) {
    const int wbf = *wflag;
    const int which = blockIdx.y;
    const int cols = which ? KLAT : QLAT;
    const void* w = which ? wkv : wq;
    ushort* p = x + (size_t)blockIdx.x * QAC + (which ? QLAT : 0);
    float ss = 0.f;
    for (int i = threadIdx.x; i < cols; i += 256) { float v = b2f(p[i]); ss += v * v; }
    #pragma unroll
    for (int off = 32; off; off >>= 1) ss += __shfl_xor(ss, off);
    __shared__ float red[4];
    const int wid = threadIdx.x >> 6, lane = threadIdx.x & 63;
    if (lane == 0) red[wid] = ss;
    __syncthreads();
    const float tot = red[0] + red[1] + red[2] + red[3];
    const float scale = rsqrtf(tot / (float)cols + 1e-6f);
    for (int i = threadIdx.x; i < cols; i += 256)
        p[i] = f2b(b2f(p[i]) * scale * ld_in(w, i, wbf));
}

// ---------------- RoPE (fp32 math on bf16 data), q + k fused ----------------
__device__ __forceinline__ void rope64(const float* in, float t, float* out) {
    #pragma unroll
    for (int i = 0; i < 32; ++i) {
        float inv = powf(10000.0f, -(float)i / 32.0f);
        float sv, cv;
        sincosf(t * inv, &sv, &cv);
        float x0 = in[2 * i], x1 = in[2 * i + 1];
        out[i]      = x0 * cv - x1 * sv;
        out[i + 32] = x1 * cv + x0 * sv;
    }
}

__global__ void rope_all_bf(ushort* __restrict__ q, const ushort* __restrict__ qac,
                            ushort* __restrict__ kpe) {
    int idx = blockIdx.x * blockDim.x + threadIdx.x;
    if (idx < SS * HH) {
        int s = idx >> 4, h = idx & 15;
        ushort* p = q + (size_t)s * QW + h * DQ + DN;
        float buf[DR], out[DR];
        #pragma unroll
        for (int i = 0; i < DR; ++i) buf[i] = b2f(p[i]);
        rope64(buf, (float)s, out);
        #pragma unroll
        for (int i = 0; i < DR; ++i) p[i] = f2b(out[i]);
    } else if (idx < SS * HH + SS) {
        int s = idx - SS * HH;
        const ushort* p = qac + (size_t)s * QAC + QLAT + KLAT;  // k_pe slice
        float buf[DR], out[DR];
        #pragma unroll
        for (int i = 0; i < DR; ++i) buf[i] = b2f(p[i]);
        rope64(buf, (float)s, out);
        ushort* dp = kpe + (size_t)s * DR;
        #pragma unroll
        for (int i = 0; i < DR; ++i) dp[i] = f2b(out[i]);
    }
}

// ---------------- build head-major K-full: kf[h][s][192] ----------------
__global__ __launch_bounds__(256) void build_kf(
    const ushort* __restrict__ kv, const ushort* __restrict__ kpe,
    ushort* __restrict__ kf) {
    int idx = blockIdx.x * 256 + threadIdx.x;       // SS*HH*24 items
    int part = idx % 24;
    int rest = idx / 24;
    int h = rest & 15, s = rest >> 4;
    short8 v;
    if (part < 16) v = *(const short8*)(kv + (size_t)s * KVW + h * KVD + part * 8);
    else           v = *(const short8*)(kpe + (size_t)s * DR + (part - 16) * 8);
    *(short8*)(kf + ((size_t)h * SS + s) * 192 + part * 8) = v;
}

// ---------------- build frag-ordered V: vt2[h][ck][idx2=kb2*8+nb][lane][8] ----------------
__global__ __launch_bounds__(256) void build_vt2(
    const ushort* __restrict__ kv, ushort* __restrict__ vt2) {
    __shared__ ushort Vl[64 * 136];
    const int ck = blockIdx.x, h = blockIdx.y;
    const int tid = threadIdx.x;
    const int lane = tid & 63, wv = tid >> 6;
    #pragma unroll
    for (int rr = 0; rr < 4; ++rr) {
        int n = rr * 256 + tid;
        int key = n >> 4, part = n & 15;
        short8 v = *(const short8*)(kv + (size_t)(ck * 64 + key) * KVW + h * KVD + DN + part * 8);
        *(short8*)&Vl[key * 136 + part * 8] = v;
    }
    __syncthreads();
    const int ln = lane & 15, quad = lane >> 4;
    ushort* dst = vt2 + (((size_t)h * 32 + ck) * 16) * 512;
    #pragma unroll
    for (int w = 0; w < 4; ++w) {
        int idx2 = wv * 4 + w;
        int kb2 = idx2 >> 3, nb = idx2 & 7;
        short8 v;
        #pragma unroll
        for (int j = 0; j < 8; ++j)
            ((ushort*)&v)[j] = Vl[(kb2 * 32 + quad * 8 + j) * 136 + nb * 16 + ln];
        *(short8*)(dst + (size_t)idx2 * 512 + lane * 8) = v;
    }
}

// ---------------- split-K MFMA flash attention (unchanged from v3) ----------
__global__ __launch_bounds__(256, 2) void attn_mfma2(
    const ushort* __restrict__ qbf, const ushort* __restrict__ kf,
    const ushort* __restrict__ vt2, ushort* __restrict__ opart,
    float* __restrict__ ml) {
    const int seg = blockIdx.x, bq = 31 - blockIdx.y, h = blockIdx.z;
    const int ctot = bq + 1;
    const int c_lo = (seg * ctot) >> 2;
    const int nch = (((seg + 1) * ctot) >> 2) - c_lo;
    if (nch <= 0) return;

    __shared__ ushort Kt[2 * KTSZ];              // 2 x 24576 B
    __shared__ ushort Pt[4][16 * PT_STRIDE];     // 9216 B

    const int tid = threadIdx.x, lane = tid & 63, wl = tid >> 6;
    const int ln = lane & 15, quad = lane >> 4;
    const int qw = bq * 64 + wl * 16;
    const int kstart = c_lo << 6;
    const float scale = 0.07216878364870322f;  // 1/sqrt(192)

    short8 aq[6];
    const ushort* qrow = qbf + (size_t)(qw + ln) * QW + h * DQ;
    #pragma unroll
    for (int kb = 0; kb < 6; ++kb)
        aq[kb] = *(const short8*)(qrow + kb * 32 + quad * 8);

    const ushort* kfh = kf + (size_t)h * SS * 192;
    const ushort* vth2 = vt2 + ((size_t)h * 32 * 16) * 512 + lane * 8;

    const int key_s = tid >> 2;
    const int swp = ((tid & 3) ^ ((tid >> 3) & 3)) * 8;
    const ushort* kg = kfh + (size_t)(kstart + key_s) * 192 + swp;
    const int swq = (quad ^ ((ln >> 1) & 3)) * 8;

    f32x4 oacc[8];
    #pragma unroll
    for (int f = 0; f < 8; ++f) oacc[f] = (f32x4){0.f, 0.f, 0.f, 0.f};
    float mrow[4] = {-INFINITY, -INFINITY, -INFINITY, -INFINITY};
    float lrow[4] = {0.f, 0.f, 0.f, 0.f};

    // prologue: stage chunk c_lo into buffer 0
    {
        ushort* kd = Kt + tid * 8;
        #pragma unroll
        for (int i = 0; i < 6; ++i)
            async16(kg + i * 32, kd + i * 2048);
        kg += (size_t)64 * 192;
    }

    for (int c = 0; c < nch; ++c) {
        const int k0 = kstart + (c << 6);
        asm volatile("s_waitcnt vmcnt(0)" ::: "memory");
        __builtin_amdgcn_s_barrier();
        asm volatile("" ::: "memory");
        if (c + 1 < nch) {
            ushort* kd = Kt + ((c + 1) & 1) * KTSZ + tid * 8;
            #pragma unroll
            for (int i = 0; i < 6; ++i)
                async16(kg + i * 32, kd + i * 2048);
            kg += (size_t)64 * 192;
        }
        const ushort* Kcur = Kt + (c & 1) * KTSZ;

        const ushort* vfr = vth2 + (size_t)(k0 >> 6) * 16 * 512;
        short8 bv0[8];
        #pragma unroll
        for (int nb = 0; nb < 8; ++nb)
            bv0[nb] = *(const short8*)(vfr + (size_t)nb * 512);
        f32x4 s[4];
        #pragma unroll
        for (int ns = 0; ns < 4; ++ns) s[ns] = (f32x4){0.f, 0.f, 0.f, 0.f};
        __builtin_amdgcn_s_setprio(1);
        #pragma unroll
        for (int ns = 0; ns < 4; ++ns)
            #pragma unroll
            for (int kb = 0; kb < 6; ++kb) {
                short8 bk = *(const short8*)&Kcur[(kb * 64 + ns * 16 + ln) * 32 + swq];
                s[ns] = __builtin_amdgcn_mfma_f32_16x16x32_bf16(aq[kb], bk, s[ns], 0, 0, 0);
            }
        __builtin_amdgcn_s_setprio(0);
        float pv[4][4], rmax[4];
        #pragma unroll
        for (int r = 0; r < 4; ++r) rmax[r] = -1e30f;
        #pragma unroll
        for (int ns = 0; ns < 4; ++ns)
            #pragma unroll
            for (int r = 0; r < 4; ++r) {
                int key = k0 + ns * 16 + ln;
                int qr = qw + quad * 4 + r;
                float v = s[ns][r] * scale;
                if (key > qr) v = -1e30f;
                pv[ns][r] = v;
                rmax[r] = fmaxf(rmax[r], v);
            }
        #pragma unroll
        for (int off = 8; off; off >>= 1)
            #pragma unroll
            for (int r = 0; r < 4; ++r)
                rmax[r] = fmaxf(rmax[r], __shfl_xor(rmax[r], off));
        float alpha[4], psum[4];
        #pragma unroll
        for (int r = 0; r < 4; ++r) {
            float mnew = fmaxf(mrow[r], rmax[r]);
            alpha[r] = __expf(mrow[r] - mnew);
            mrow[r] = mnew;
        }
        #pragma unroll
        for (int ns = 0; ns < 4; ++ns)
            #pragma unroll
            for (int r = 0; r < 4; ++r)
                pv[ns][r] = __expf(pv[ns][r] - mrow[r]);
        #pragma unroll
        for (int r = 0; r < 4; ++r)
            psum[r] = (pv[0][r] + pv[1][r]) + (pv[2][r] + pv[3][r]);
        #pragma unroll
        for (int off = 8; off; off >>= 1)
            #pragma unroll
            for (int r = 0; r < 4; ++r)
                psum[r] += __shfl_xor(psum[r], off);
        #pragma unroll
        for (int r = 0; r < 4; ++r) lrow[r] = lrow[r] * alpha[r] + psum[r];
        #pragma unroll
        for (int f = 0; f < 8; ++f)
            #pragma unroll
            for (int r = 0; r < 4; ++r) oacc[f][r] *= alpha[r];
        #pragma unroll
        for (int ns = 0; ns < 4; ++ns)
            #pragma unroll
            for (int r = 0; r < 4; ++r)
                Pt[wl][(quad * 4 + r) * PT_STRIDE + ns * 16 + ln] = f2b(pv[ns][r]);
        short8 bv1[8];
        #pragma unroll
        for (int nb = 0; nb < 8; ++nb)
            bv1[nb] = *(const short8*)(vfr + (size_t)(8 + nb) * 512);
        short8 pa0 = *(const short8*)&Pt[wl][ln * PT_STRIDE + quad * 8];
        short8 pa1 = *(const short8*)&Pt[wl][ln * PT_STRIDE + 32 + quad * 8];
        __builtin_amdgcn_s_setprio(1);
        #pragma unroll
        for (int nb = 0; nb < 8; ++nb)
            oacc[nb] = __builtin_amdgcn_mfma_f32_16x16x32_bf16(pa0, bv0[nb], oacc[nb], 0, 0, 0);
        #pragma unroll
        for (int nb = 0; nb < 8; ++nb)
            oacc[nb] = __builtin_amdgcn_mfma_f32_16x16x32_bf16(pa1, bv1[nb], oacc[nb], 0, 0, 0);
        __builtin_amdgcn_s_setprio(0);
    }

    const size_t pbase = (((size_t)h * 32 + bq) * NSEG + seg) * 64;
    #pragma unroll
    for (int nb = 0; nb < 8; ++nb)
        #pragma unroll
        for (int r = 0; r < 4; ++r)
            opart[(pbase + wl * 16 + quad * 4 + r) * 128 + nb * 16 + ln] = f2b(oacc[nb][r]);
    if (ln == 0) {
        #pragma unroll
        for (int r = 0; r < 4; ++r) {
            ml[(pbase + wl * 16 + quad * 4 + r) * 2]     = mrow[r];
            ml[(pbase + wl * 16 + quad * 4 + r) * 2 + 1] = lrow[r];
        }
    }
}

// ---------------- merge partials -> obf ----------------
// seg s contributes to row-tile bq iff floor((s+1)*ctot/4) > floor(s*ctot/4)
// (must match attn_mfma2's chunk-split predicate exactly)
__global__ __launch_bounds__(256) void merge_attn(
    const ushort* __restrict__ opart, const float* __restrict__ ml,
    ushort* __restrict__ obf) {
    const int q = blockIdx.x;
    const int bq = q >> 6, row = q & 63;
    const int ctot = bq + 1;
    const int t = threadIdx.x;
    #pragma unroll
    for (int pp = 0; pp < 8; ++pp) {
        int idx = pp * 256 + t;            // 0..2047 = h*128 + d
        int h = idx >> 7, d = idx & 127;
        size_t rbase = (((size_t)h * 32 + bq) * NSEG) * 64 + row;  // + s*64
        float M = -1e30f;
        #pragma unroll
        for (int s = 0; s < NSEG; ++s) {
            if ((((s + 1) * ctot) >> 2) > ((s * ctot) >> 2))
                M = fmaxf(M, ml[(rbase + (size_t)s * 64) * 2]);
        }
        float L = 0.f, acc = 0.f;
        #pragma unroll
        for (int s = 0; s < NSEG; ++s) {
            if ((((s + 1) * ctot) >> 2) > ((s * ctot) >> 2)) {
                size_t ri = rbase + (size_t)s * 64;
                float w = __expf(ml[ri * 2] - M);
                L += w * ml[ri * 2 + 1];
                acc += w * b2f(opart[ri * 128 + d]);
            }
        }
        obf[(size_t)q * OW + h * DV + d] = f2b(acc / L);
    }
}

// ---------------- launch ----------------
extern "C" void kernel_launch(void* const* d_in, const int* in_sizes, int n_in,
                              void* d_out, int out_size, void* d_ws, size_t ws_size,
                              hipStream_t stream) {
    const void* x       = d_in[0];
    const void* w_q_a   = d_in[1];
    const void* q_a_ln  = d_in[2];
    const void* w_q_b   = d_in[3];
    const void* w_kv_a  = d_in[4];
    const void* kv_a_ln = d_in[5];
    const void* w_kv_b  = d_in[6];
    const void* w_out   = d_in[7];

    char* ws = (char*)d_ws;
    int*    flag  = (int*)ws;
    ushort* qbf   = (ushort*)(ws + 256);             // S*QW
    ushort* obf   = qbf   + (size_t)SS * QW;         // S*OW
    ushort* wqat  = obf   + (size_t)SS * OW;         // QLAT*EE  } contiguous ->
    ushort* wkvat = wqat  + (size_t)QLAT * EE;       // CKVW*EE  } merged Bt[2112][EE]
    ushort* wqbt  = wkvat + (size_t)CKVW * EE;       // QW*QLAT
    ushort* wkvbt = wqbt  + (size_t)QW * QLAT;       // KVW*KLAT
    ushort* woutt = wkvbt + (size_t)KVW * KLAT;      // EE*OW
    ushort* kf    = woutt + (size_t)EE * OW;         // HH*SS*192
    ushort* vt2   = kf    + (size_t)HH * SS * 192;   // HH*SS*DV (frag-ordered)
    float*  ml    = (float*)(vt2 + (size_t)HH * SS * DV);  // HH*32*NSEG*64*2 floats
    // overlay zone (all dead before attention writes opart):
    ushort* qac   = (ushort*)(ml + (size_t)HH * 32 * NSEG * 64 * 2);  // S*QAC
    ushort* xbf   = qac   + (size_t)SS * QAC;        // S*EE
    ushort* kvbf  = xbf   + (size_t)SS * EE;         // S*KVW
    ushort* kpebf = kvbf  + (size_t)SS * KVW;        // S*DR
    ushort* opart = qac;  // HH*32*NSEG*64*128 halfs <= overlay span (17.04M)

    detect_dtype<<<1, 1, 0, stream>>>((const unsigned int*)q_a_ln, flag);

    conv_x_bf<<<(SS * EE / 4 + 255) / 256, 256, 0, stream>>>(x, xbf, SS * EE, flag);
    // all 5 weight transposes in one launch (z selects; max tiles 64 x 32)
    transpose5_bf<<<dim3(64, 32, 5), 256, 0, stream>>>(
        w_q_a, w_kv_a, w_q_b, w_kv_b, w_out,
        wqat, wkvat, wqbt, wkvbt, woutt, flag);

    // qac = x @ [w_q_a | w_kv_a]  (2048 x 2112, K=2048), merged, 544 blocks
    gemm_bf64<<<dim3((QAC + 127) / 128, SS / 64), 256, 0, stream>>>(
        xbf, wqat, qac, QAC, EE, EE, EE, QAC, 1, nullptr);

    rmsnorm2_bf<<<dim3(SS, 2), 256, 0, stream>>>(qac, q_a_ln, kv_a_ln, flag);

    // qbf = qa_norm @ w_q_b (2048x3072, K=1536), A = qac cols 0..1536
    gemm_bf<<<dim3(QW / 128, SS / 128), 256, 0, stream>>>(
        qac, wqbt, qbf, QW, QLAT, QAC, QLAT, QW, 1, nullptr);
    // kvbf = ckv_norm @ w_kv_b (2048x4096, K=512), A = qac cols 1536..2048
    gemm_bf<<<dim3(KVW / 128, SS / 128), 256, 0, stream>>>(
        qac + QLAT, wkvbt, kvbf, KVW, KLAT, QAC, KLAT, KVW, 1, nullptr);

    rope_all_bf<<<(SS * HH + SS + 255) / 256, 256, 0, stream>>>(qbf, qac, kpebf);

    build_kf<<<SS * HH * 24 / 256, 256, 0, stream>>>(kvbf, kpebf, kf);
    build_vt2<<<dim3(SS / 64, HH), 256, 0, stream>>>(kvbf, vt2);

    attn_mfma2<<<dim3(NSEG, SS / 64, HH), 256, 0, stream>>>(qbf, kf, vt2, opart, ml);
    merge_attn<<<SS, 256, 0, stream>>>(opart, ml, obf);

    // out = o @ w_out (2048x2048, K=2048), 512 blocks via 64-tile
    gemm_bf64<<<dim3(EE / 128, SS / 64), 256, 0, stream>>>(
        obf, woutt, d_out, EE, OW, OW, OW, EE, 2, flag);
}

// Round 4
// 410.342 us; speedup vs baseline: 1.3636x; 1.0171x over previous
//
#include <hip/hip_runtime.h>
#include <hip/hip_bf16.h>
#include <math.h>

// Problem constants (fixed shapes)
#define SS   2048   // sequence length
#define EE   2048   // embed dim
#define HH   16     // heads
#define QLAT 1536   // q latent
#define KLAT 512    // kv latent
#define DN   128
#define DR   64
#define DV   128
#define DQ   192    // DN+DR
#define KVD  256    // DN+DV
#define CKVW 576    // KLAT+DR
#define QW   3072   // HH*DQ
#define KVW  4096   // HH*KVD
#define OW   2048   // HH*DV
#define QAC  2112   // QLAT + CKVW (merged a-proj output width)

#define NSEG 4      // key segments (flash-decoding split)
#define PT_STRIDE 72
#define KTSZ (6 * 64 * 32)   // one K-chunk in LDS (ushorts)

typedef __attribute__((ext_vector_type(8))) short short8;
typedef __attribute__((ext_vector_type(4))) float f32x4;

// ---------------- helpers ----------------
__global__ void detect_dtype(const unsigned int* __restrict__ lnw, int* flag) {
    *flag = (lnw[0] == 0x3F803F80u) ? 1 : 0;  // bf16 pair of 1.0 vs fp32 1.0
}

__device__ __forceinline__ float ld_in(const void* p, size_t i, int bf) {
    if (bf) return __bfloat162float(((const __hip_bfloat16*)p)[i]);
    return ((const float*)p)[i];
}

__device__ __forceinline__ ushort f2b(float v) {
    __hip_bfloat16 b = __float2bfloat16(v);
    return *(ushort*)&b;
}
__device__ __forceinline__ float b2f(ushort u) {
    __hip_bfloat16 b = *(__hip_bfloat16*)&u;
    return __bfloat162float(b);
}

// async global->LDS, 16 B per lane; LDS dst must be wave-uniform base + lane*16
__device__ __forceinline__ void async16(const ushort* g, ushort* l) {
    __builtin_amdgcn_global_load_lds(
        (const __attribute__((address_space(1))) void*)g,
        (__attribute__((address_space(3))) void*)l, 16, 0, 0);
}

// ---------------- input convert (x -> bf16) ----------------
__global__ __launch_bounds__(256) void conv_x_bf(
    const void* __restrict__ src, ushort* __restrict__ dst, int n, const int* flag) {
    const int bf = *flag;
    int i = (blockIdx.x * 256 + threadIdx.x) * 4;
    if (i >= n) return;
    ushort4 u;
    u.x = f2b(ld_in(src, i + 0, bf));
    u.y = f2b(ld_in(src, i + 1, bf));
    u.z = f2b(ld_in(src, i + 2, bf));
    u.w = f2b(ld_in(src, i + 3, bf));
    *(ushort4*)(dst + i) = u;
}

// ---------------- batched weight transpose+convert: in[R][C] -> out[C][R] bf16 ----
__global__ __launch_bounds__(256) void transpose5_bf(
    const void* __restrict__ s0, const void* __restrict__ s1,
    const void* __restrict__ s2, const void* __restrict__ s3,
    const void* __restrict__ s4,
    ushort* __restrict__ d0, ushort* __restrict__ d1, ushort* __restrict__ d2,
    ushort* __restrict__ d3, ushort* __restrict__ d4,
    const int* flag) {
    const int z = blockIdx.z;
    const void* in; ushort* out; int R, C;
    switch (z) {
        case 0:  in = s0; out = d0; R = EE;   C = QLAT; break;  // w_q_a
        case 1:  in = s1; out = d1; R = EE;   C = CKVW; break;  // w_kv_a
        case 2:  in = s2; out = d2; R = QLAT; C = QW;   break;  // w_q_b
        case 3:  in = s3; out = d3; R = KLAT; C = KVW;  break;  // w_kv_b
        default: in = s4; out = d4; R = OW;   C = EE;   break;  // w_out
    }
    const int c0 = blockIdx.x * 64, r0 = blockIdx.y * 64;
    if (c0 >= C || r0 >= R) return;
    const int bf = *flag;
    __shared__ ushort t[64][66];
    const int lane = threadIdx.x & 63, grp = threadIdx.x >> 6;
    #pragma unroll
    for (int p = 0; p < 16; ++p) {
        int r = p * 4 + grp;
        t[lane][r] = f2b(ld_in(in, (size_t)(r0 + r) * C + c0 + lane, bf));
    }
    __syncthreads();
    const int ro = (threadIdx.x & 31) * 2, co = threadIdx.x >> 5;
    #pragma unroll
    for (int p = 0; p < 8; ++p) {
        int c = p * 8 + co;
        ushort2 u = *(const ushort2*)&t[c][ro];
        *(ushort2*)&out[(size_t)(c0 + c) * R + r0 + ro] = u;
    }
}

// ---------------- bf16 MFMA GEMM 128x128, LDS double-buffered ----------------
__global__ __launch_bounds__(256) void gemm_bf(
    const ushort* __restrict__ A, const ushort* __restrict__ Bt,
    void* __restrict__ C, int N, int K, int lda, int ldb, int ldc,
    int cmode, const int* __restrict__ cflag) {
    __shared__ ushort As[2][128 * 32];
    __shared__ ushort Bs[2][128 * 32];
    const int tid = threadIdx.x;
    const int bm = blockIdx.y * 128, bn = blockIdx.x * 128;
    const int lane = tid & 63, wv = tid >> 6;
    const int wm = (wv & 1) * 64, wn = (wv >> 1) * 64;
    const int ln = lane & 15, quad = lane >> 4;

    f32x4 acc[4][4];
    #pragma unroll
    for (int i = 0; i < 4; ++i)
        #pragma unroll
        for (int j = 0; j < 4; ++j) acc[i][j] = (f32x4){0.f, 0.f, 0.f, 0.f};

    const int srow = tid >> 2;
    const int spart = (((tid & 3) ^ ((tid >> 3) & 3))) * 8;  // swizzled source 16B part
    const ushort* Ag0 = A  + (size_t)(bm + srow) * lda + spart;
    const ushort* Ag1 = Ag0 + (size_t)64 * lda;
    const ushort* Bg0 = Bt + (size_t)(bn + srow) * ldb + spart;
    const ushort* Bg1 = Bg0 + (size_t)64 * ldb;
    const bool bok0 = (bn + srow) < N;
    const bool bok1 = (bn + 64 + srow) < N;
    const int swq = (quad ^ ((ln >> 1) & 3)) * 8;  // swizzled read part
    const int nsteps = K >> 5;

    {
        ushort* Asl = As[0] + tid * 8;
        ushort* Bsl = Bs[0] + tid * 8;
        async16(Ag0, Asl);
        async16(Ag1, Asl + 2048);
        if (bok0) async16(Bg0, Bsl);
        if (bok1) async16(Bg1, Bsl + 2048);
    }

    for (int c = 0; c < nsteps; ++c) {
        asm volatile("s_waitcnt vmcnt(0)" ::: "memory");
        __builtin_amdgcn_s_barrier();
        asm volatile("" ::: "memory");
        if (c + 1 < nsteps) {
            const int k1 = (c + 1) << 5;
            const int nb = (c + 1) & 1;
            ushort* Asl = As[nb] + tid * 8;
            ushort* Bsl = Bs[nb] + tid * 8;
            async16(Ag0 + k1, Asl);
            async16(Ag1 + k1, Asl + 2048);
            if (bok0) async16(Bg0 + k1, Bsl);
            if (bok1) async16(Bg1 + k1, Bsl + 2048);
        }
        const ushort* Ac = As[c & 1];
        const ushort* Bc = Bs[c & 1];
        short8 af[4], bfr[4];
        #pragma unroll
        for (int t = 0; t < 4; ++t) {
            af[t]  = *(const short8*)&Ac[(wm + t * 16 + ln) * 32 + swq];
            bfr[t] = *(const short8*)&Bc[(wn + t * 16 + ln) * 32 + swq];
        }
        __builtin_amdgcn_s_setprio(1);
        #pragma unroll
        for (int i = 0; i < 4; ++i)
            #pragma unroll
            for (int j = 0; j < 4; ++j)
                acc[i][j] = __builtin_amdgcn_mfma_f32_16x16x32_bf16(af[i], bfr[j], acc[i][j], 0, 0, 0);
        __builtin_amdgcn_s_setprio(0);
    }

    const int cbf = (cmode == 2) ? *cflag : cmode;
    #pragma unroll
    for (int i = 0; i < 4; ++i) {
        #pragma unroll
        for (int r = 0; r < 4; ++r) {
            const int m = bm + wm + i * 16 + quad * 4 + r;
            #pragma unroll
            for (int j = 0; j < 4; ++j) {
                const int n = bn + wn + j * 16 + ln;
                if (n < N) {
                    if (cbf) ((ushort*)C)[(size_t)m * ldc + n] = f2b(acc[i][j][r]);
                    else     ((float*)C)[(size_t)m * ldc + n] = acc[i][j][r];
                }
            }
        }
    }
}

// ---------------- bf16 MFMA GEMM 64x128, LDS double-buffered ----------------
__global__ __launch_bounds__(256) void gemm_bf64(
    const ushort* __restrict__ A, const ushort* __restrict__ Bt,
    void* __restrict__ C, int N, int K, int lda, int ldb, int ldc,
    int cmode, const int* __restrict__ cflag) {
    __shared__ ushort As[2][64 * 32];
    __shared__ ushort Bs[2][128 * 32];
    const int tid = threadIdx.x;
    const int bm = blockIdx.y * 64, bn = blockIdx.x * 128;
    const int lane = tid & 63, wv = tid >> 6;
    const int wm = (wv & 1) * 32, wn = (wv >> 1) * 64;
    const int ln = lane & 15, quad = lane >> 4;

    f32x4 acc[2][4];
    #pragma unroll
    for (int i = 0; i < 2; ++i)
        #pragma unroll
        for (int j = 0; j < 4; ++j) acc[i][j] = (f32x4){0.f, 0.f, 0.f, 0.f};

    const int srow = tid >> 2;
    const int spart = (((tid & 3) ^ ((tid >> 3) & 3))) * 8;
    const ushort* Ag0 = A  + (size_t)(bm + srow) * lda + spart;
    const ushort* Bg0 = Bt + (size_t)(bn + srow) * ldb + spart;
    const ushort* Bg1 = Bg0 + (size_t)64 * ldb;
    const bool bok0 = (bn + srow) < N;
    const bool bok1 = (bn + 64 + srow) < N;
    const int swq = (quad ^ ((ln >> 1) & 3)) * 8;
    const int nsteps = K >> 5;

    {
        ushort* Asl = As[0] + tid * 8;
        ushort* Bsl = Bs[0] + tid * 8;
        async16(Ag0, Asl);
        if (bok0) async16(Bg0, Bsl);
        if (bok1) async16(Bg1, Bsl + 2048);
    }

    for (int c = 0; c < nsteps; ++c) {
        asm volatile("s_waitcnt vmcnt(0)" ::: "memory");
        __builtin_amdgcn_s_barrier();
        asm volatile("" ::: "memory");
        if (c + 1 < nsteps) {
            const int k1 = (c + 1) << 5;
            const int nb = (c + 1) & 1;
            ushort* Asl = As[nb] + tid * 8;
            ushort* Bsl = Bs[nb] + tid * 8;
            async16(Ag0 + k1, Asl);
            if (bok0) async16(Bg0 + k1, Bsl);
            if (bok1) async16(Bg1 + k1, Bsl + 2048);
        }
        const ushort* Ac = As[c & 1];
        const ushort* Bc = Bs[c & 1];
        short8 af[2], bfr[4];
        #pragma unroll
        for (int t = 0; t < 2; ++t)
            af[t] = *(const short8*)&Ac[(wm + t * 16 + ln) * 32 + swq];
        #pragma unroll
        for (int t = 0; t < 4; ++t)
            bfr[t] = *(const short8*)&Bc[(wn + t * 16 + ln) * 32 + swq];
        __builtin_amdgcn_s_setprio(1);
        #pragma unroll
        for (int i = 0; i < 2; ++i)
            #pragma unroll
            for (int j = 0; j < 4; ++j)
                acc[i][j] = __builtin_amdgcn_mfma_f32_16x16x32_bf16(af[i], bfr[j], acc[i][j], 0, 0, 0);
        __builtin_amdgcn_s_setprio(0);
    }

    const int cbf = (cmode == 2) ? *cflag : cmode;
    #pragma unroll
    for (int i = 0; i < 2; ++i) {
        #pragma unroll
        for (int r = 0; r < 4; ++r) {
            const int m = bm + wm + i * 16 + quad * 4 + r;
            #pragma unroll
            for (int j = 0; j < 4; ++j) {
                const int n = bn + wn + j * 16 + ln;
                if (n < N) {
                    if (cbf) ((ushort*)C)[(size_t)m * ldc + n] = f2b(acc[i][j][r]);
                    else     ((float*)C)[(size_t)m * ldc + n] = acc[i][j][r];
                }
            }
        }
    }
}

// ---------------- RMSNorm bf16 in-place (fp32 math), both norms fused ------
__global__ __launch_bounds__(256) void rmsnorm2_bf(
    ushort* __restrict__ x, const void* __restrict__ wq,
    const void* __restrict__ wkv, const int* wflag) {
    const int wbf = *wflag;
    const int which = blockIdx.y;
    const int cols = which ? KLAT : QLAT;
    const void* w = which ? wkv : wq;
    ushort* p = x + (size_t)blockIdx.x * QAC + (which ? QLAT : 0);
    float ss = 0.f;
    for (int i = threadIdx.x; i < cols; i += 256) { float v = b2f(p[i]); ss += v * v; }
    #pragma unroll
    for (int off = 32; off; off >>= 1) ss += __shfl_xor(ss, off);
    __shared__ float red[4];
    const int wid = threadIdx.x >> 6, lane = threadIdx.x & 63;
    if (lane == 0) red[wid] = ss;
    __syncthreads();
    const float tot = red[0] + red[1] + red[2] + red[3];
    const float scale = rsqrtf(tot / (float)cols + 1e-6f);
    for (int i = threadIdx.x; i < cols; i += 256)
        p[i] = f2b(b2f(p[i]) * scale * ld_in(w, i, wbf));
}

// ---------------- RoPE v4: table + vectorized apply -------------------------
// Old rope_all_bf was the LARGEST dispatch (117 us, VALUBusy 0.05%, Occ 0.07%):
// float buf[64]/out[64] lived in scratch (VGPR=64) and 32x powf+sincosf per
// thread (args up to 2047 rad -> slow-path reduction) at 0.5 blocks/CU.
// Fix: cos/sin table computed ONCE per (s,i) (16x less transcendental work
// than per-head recompute), apply kernel is pure vectorized FMA.
__global__ __launch_bounds__(256) void rope_tab(float* __restrict__ tab) {
    int idx = blockIdx.x * 256 + threadIdx.x;   // SS*32
    int s = idx >> 5, i = idx & 31;
    float inv = powf(10000.0f, -(float)i / 32.0f);
    float sv, cv;
    sincosf((float)s * inv, &sv, &cv);
    tab[idx * 2]     = cv;
    tab[idx * 2 + 1] = sv;
}

// one thread owns one 64-elem rope block (read-all-then-write: the i->{i,i+32}
// permutation makes partial in-place rewrite hazardous)
__device__ __forceinline__ void rope_block(
    const ushort* __restrict__ src, ushort* __restrict__ dst,
    const float* __restrict__ tb) {
    short8 vin[8];
    #pragma unroll
    for (int t = 0; t < 8; ++t) vin[t] = *(const short8*)(src + t * 8);
    short8 lo[4], hi[4];
    #pragma unroll
    for (int t = 0; t < 4; ++t) {
        #pragma unroll
        for (int j = 0; j < 8; ++j) {
            const int i = t * 8 + j;
            float cv = tb[2 * i], sv = tb[2 * i + 1];
            ushort u0 = ((const ushort*)&vin[(2 * i) >> 3])[(2 * i) & 7];
            ushort u1 = ((const ushort*)&vin[(2 * i + 1) >> 3])[(2 * i + 1) & 7];
            float x0 = b2f(u0), x1 = b2f(u1);
            lo[t][j] = (short)f2b(x0 * cv - x1 * sv);
            hi[t][j] = (short)f2b(x1 * cv + x0 * sv);
        }
    }
    #pragma unroll
    for (int t = 0; t < 4; ++t) {
        *(short8*)(dst + t * 8)      = lo[t];
        *(short8*)(dst + 32 + t * 8) = hi[t];
    }
}

__global__ __launch_bounds__(256) void rope_apply(
    ushort* __restrict__ q, const ushort* __restrict__ qac,
    ushort* __restrict__ kpe, const float* __restrict__ tab) {
    int idx = blockIdx.x * blockDim.x + threadIdx.x;
    if (idx < SS * HH) {
        int s = idx >> 4, h = idx & 15;
        ushort* p = q + (size_t)s * QW + h * DQ + DN;
        rope_block(p, p, tab + s * 64);
    } else if (idx < SS * HH + SS) {
        int s = idx - SS * HH;
        rope_block(qac + (size_t)s * QAC + QLAT + KLAT,
                   kpe + (size_t)s * DR, tab + s * 64);
    }
}

// ---------------- build head-major K-full: kf[h][s][192] ----------------
__global__ __launch_bounds__(256) void build_kf(
    const ushort* __restrict__ kv, const ushort* __restrict__ kpe,
    ushort* __restrict__ kf) {
    int idx = blockIdx.x * 256 + threadIdx.x;       // SS*HH*24 items
    int part = idx % 24;
    int rest = idx / 24;
    int h = rest & 15, s = rest >> 4;
    short8 v;
    if (part < 16) v = *(const short8*)(kv + (size_t)s * KVW + h * KVD + part * 8);
    else           v = *(const short8*)(kpe + (size_t)s * DR + (part - 16) * 8);
    *(short8*)(kf + ((size_t)h * SS + s) * 192 + part * 8) = v;
}

// ---------------- build frag-ordered V: vt2[h][ck][idx2=kb2*8+nb][lane][8] ----------------
__global__ __launch_bounds__(256) void build_vt2(
    const ushort* __restrict__ kv, ushort* __restrict__ vt2) {
    __shared__ ushort Vl[64 * 136];
    const int ck = blockIdx.x, h = blockIdx.y;
    const int tid = threadIdx.x;
    const int lane = tid & 63, wv = tid >> 6;
    #pragma unroll
    for (int rr = 0; rr < 4; ++rr) {
        int n = rr * 256 + tid;
        int key = n >> 4, part = n & 15;
        short8 v = *(const short8*)(kv + (size_t)(ck * 64 + key) * KVW + h * KVD + DN + part * 8);
        *(short8*)&Vl[key * 136 + part * 8] = v;
    }
    __syncthreads();
    const int ln = lane & 15, quad = lane >> 4;
    ushort* dst = vt2 + (((size_t)h * 32 + ck) * 16) * 512;
    #pragma unroll
    for (int w = 0; w < 4; ++w) {
        int idx2 = wv * 4 + w;
        int kb2 = idx2 >> 3, nb = idx2 & 7;
        short8 v;
        #pragma unroll
        for (int j = 0; j < 8; ++j)
            ((ushort*)&v)[j] = Vl[(kb2 * 32 + quad * 8 + j) * 136 + nb * 16 + ln];
        *(short8*)(dst + (size_t)idx2 * 512 + lane * 8) = v;
    }
}

// ---------------- split-K MFMA flash attention (unchanged) ----------
__global__ __launch_bounds__(256, 2) void attn_mfma2(
    const ushort* __restrict__ qbf, const ushort* __restrict__ kf,
    const ushort* __restrict__ vt2, ushort* __restrict__ opart,
    float* __restrict__ ml) {
    const int seg = blockIdx.x, bq = 31 - blockIdx.y, h = blockIdx.z;
    const int ctot = bq + 1;
    const int c_lo = (seg * ctot) >> 2;
    const int nch = (((seg + 1) * ctot) >> 2) - c_lo;
    if (nch <= 0) return;

    __shared__ ushort Kt[2 * KTSZ];              // 2 x 24576 B
    __shared__ ushort Pt[4][16 * PT_STRIDE];     // 9216 B

    const int tid = threadIdx.x, lane = tid & 63, wl = tid >> 6;
    const int ln = lane & 15, quad = lane >> 4;
    const int qw = bq * 64 + wl * 16;
    const int kstart = c_lo << 6;
    const float scale = 0.07216878364870322f;  // 1/sqrt(192)

    short8 aq[6];
    const ushort* qrow = qbf + (size_t)(qw + ln) * QW + h * DQ;
    #pragma unroll
    for (int kb = 0; kb < 6; ++kb)
        aq[kb] = *(const short8*)(qrow + kb * 32 + quad * 8);

    const ushort* kfh = kf + (size_t)h * SS * 192;
    const ushort* vth2 = vt2 + ((size_t)h * 32 * 16) * 512 + lane * 8;

    const int key_s = tid >> 2;
    const int swp = ((tid & 3) ^ ((tid >> 3) & 3)) * 8;
    const ushort* kg = kfh + (size_t)(kstart + key_s) * 192 + swp;
    const int swq = (quad ^ ((ln >> 1) & 3)) * 8;

    f32x4 oacc[8];
    #pragma unroll
    for (int f = 0; f < 8; ++f) oacc[f] = (f32x4){0.f, 0.f, 0.f, 0.f};
    float mrow[4] = {-INFINITY, -INFINITY, -INFINITY, -INFINITY};
    float lrow[4] = {0.f, 0.f, 0.f, 0.f};

    {
        ushort* kd = Kt + tid * 8;
        #pragma unroll
        for (int i = 0; i < 6; ++i)
            async16(kg + i * 32, kd + i * 2048);
        kg += (size_t)64 * 192;
    }

    for (int c = 0; c < nch; ++c) {
        const int k0 = kstart + (c << 6);
        asm volatile("s_waitcnt vmcnt(0)" ::: "memory");
        __builtin_amdgcn_s_barrier();
        asm volatile("" ::: "memory");
        if (c + 1 < nch) {
            ushort* kd = Kt + ((c + 1) & 1) * KTSZ + tid * 8;
            #pragma unroll
            for (int i = 0; i < 6; ++i)
                async16(kg + i * 32, kd + i * 2048);
            kg += (size_t)64 * 192;
        }
        const ushort* Kcur = Kt + (c & 1) * KTSZ;

        const ushort* vfr = vth2 + (size_t)(k0 >> 6) * 16 * 512;
        short8 bv0[8];
        #pragma unroll
        for (int nb = 0; nb < 8; ++nb)
            bv0[nb] = *(const short8*)(vfr + (size_t)nb * 512);
        f32x4 s[4];
        #pragma unroll
        for (int ns = 0; ns < 4; ++ns) s[ns] = (f32x4){0.f, 0.f, 0.f, 0.f};
        __builtin_amdgcn_s_setprio(1);
        #pragma unroll
        for (int ns = 0; ns < 4; ++ns)
            #pragma unroll
            for (int kb = 0; kb < 6; ++kb) {
                short8 bk = *(const short8*)&Kcur[(kb * 64 + ns * 16 + ln) * 32 + swq];
                s[ns] = __builtin_amdgcn_mfma_f32_16x16x32_bf16(aq[kb], bk, s[ns], 0, 0, 0);
            }
        __builtin_amdgcn_s_setprio(0);
        float pv[4][4], rmax[4];
        #pragma unroll
        for (int r = 0; r < 4; ++r) rmax[r] = -1e30f;
        #pragma unroll
        for (int ns = 0; ns < 4; ++ns)
            #pragma unroll
            for (int r = 0; r < 4; ++r) {
                int key = k0 + ns * 16 + ln;
                int qr = qw + quad * 4 + r;
                float v = s[ns][r] * scale;
                if (key > qr) v = -1e30f;
                pv[ns][r] = v;
                rmax[r] = fmaxf(rmax[r], v);
            }
        #pragma unroll
        for (int off = 8; off; off >>= 1)
            #pragma unroll
            for (int r = 0; r < 4; ++r)
                rmax[r] = fmaxf(rmax[r], __shfl_xor(rmax[r], off));
        float alpha[4], psum[4];
        #pragma unroll
        for (int r = 0; r < 4; ++r) {
            float mnew = fmaxf(mrow[r], rmax[r]);
            alpha[r] = __expf(mrow[r] - mnew);
            mrow[r] = mnew;
        }
        #pragma unroll
        for (int ns = 0; ns < 4; ++ns)
            #pragma unroll
            for (int r = 0; r < 4; ++r)
                pv[ns][r] = __expf(pv[ns][r] - mrow[r]);
        #pragma unroll
        for (int r = 0; r < 4; ++r)
            psum[r] = (pv[0][r] + pv[1][r]) + (pv[2][r] + pv[3][r]);
        #pragma unroll
        for (int off = 8; off; off >>= 1)
            #pragma unroll
            for (int r = 0; r < 4; ++r)
                psum[r] += __shfl_xor(psum[r], off);
        #pragma unroll
        for (int r = 0; r < 4; ++r) lrow[r] = lrow[r] * alpha[r] + psum[r];
        #pragma unroll
        for (int f = 0; f < 8; ++f)
            #pragma unroll
            for (int r = 0; r < 4; ++r) oacc[f][r] *= alpha[r];
        #pragma unroll
        for (int ns = 0; ns < 4; ++ns)
            #pragma unroll
            for (int r = 0; r < 4; ++r)
                Pt[wl][(quad * 4 + r) * PT_STRIDE + ns * 16 + ln] = f2b(pv[ns][r]);
        short8 bv1[8];
        #pragma unroll
        for (int nb = 0; nb < 8; ++nb)
            bv1[nb] = *(const short8*)(vfr + (size_t)(8 + nb) * 512);
        short8 pa0 = *(const short8*)&Pt[wl][ln * PT_STRIDE + quad * 8];
        short8 pa1 = *(const short8*)&Pt[wl][ln * PT_STRIDE + 32 + quad * 8];
        __builtin_amdgcn_s_setprio(1);
        #pragma unroll
        for (int nb = 0; nb < 8; ++nb)
            oacc[nb] = __builtin_amdgcn_mfma_f32_16x16x32_bf16(pa0, bv0[nb], oacc[nb], 0, 0, 0);
        #pragma unroll
        for (int nb = 0; nb < 8; ++nb)
            oacc[nb] = __builtin_amdgcn_mfma_f32_16x16x32_bf16(pa1, bv1[nb], oacc[nb], 0, 0, 0);
        __builtin_amdgcn_s_setprio(0);
    }

    const size_t pbase = (((size_t)h * 32 + bq) * NSEG + seg) * 64;
    #pragma unroll
    for (int nb = 0; nb < 8; ++nb)
        #pragma unroll
        for (int r = 0; r < 4; ++r)
            opart[(pbase + wl * 16 + quad * 4 + r) * 128 + nb * 16 + ln] = f2b(oacc[nb][r]);
    if (ln == 0) {
        #pragma unroll
        for (int r = 0; r < 4; ++r) {
            ml[(pbase + wl * 16 + quad * 4 + r) * 2]     = mrow[r];
            ml[(pbase + wl * 16 + quad * 4 + r) * 2 + 1] = lrow[r];
        }
    }
}

// ---------------- merge partials -> obf ----------------
__global__ __launch_bounds__(256) void merge_attn(
    const ushort* __restrict__ opart, const float* __restrict__ ml,
    ushort* __restrict__ obf) {
    const int q = blockIdx.x;
    const int bq = q >> 6, row = q & 63;
    const int ctot = bq + 1;
    const int t = threadIdx.x;
    #pragma unroll
    for (int pp = 0; pp < 8; ++pp) {
        int idx = pp * 256 + t;            // 0..2047 = h*128 + d
        int h = idx >> 7, d = idx & 127;
        size_t rbase = (((size_t)h * 32 + bq) * NSEG) * 64 + row;  // + s*64
        float M = -1e30f;
        #pragma unroll
        for (int s = 0; s < NSEG; ++s) {
            if ((((s + 1) * ctot) >> 2) > ((s * ctot) >> 2))
                M = fmaxf(M, ml[(rbase + (size_t)s * 64) * 2]);
        }
        float L = 0.f, acc = 0.f;
        #pragma unroll
        for (int s = 0; s < NSEG; ++s) {
            if ((((s + 1) * ctot) >> 2) > ((s * ctot) >> 2)) {
                size_t ri = rbase + (size_t)s * 64;
                float w = __expf(ml[ri * 2] - M);
                L += w * ml[ri * 2 + 1];
                acc += w * b2f(opart[ri * 128 + d]);
            }
        }
        obf[(size_t)q * OW + h * DV + d] = f2b(acc / L);
    }
}

// ---------------- launch ----------------
extern "C" void kernel_launch(void* const* d_in, const int* in_sizes, int n_in,
                              void* d_out, int out_size, void* d_ws, size_t ws_size,
                              hipStream_t stream) {
    const void* x       = d_in[0];
    const void* w_q_a   = d_in[1];
    const void* q_a_ln  = d_in[2];
    const void* w_q_b   = d_in[3];
    const void* w_kv_a  = d_in[4];
    const void* kv_a_ln = d_in[5];
    const void* w_kv_b  = d_in[6];
    const void* w_out   = d_in[7];

    char* ws = (char*)d_ws;
    int*    flag  = (int*)ws;
    ushort* qbf   = (ushort*)(ws + 256);             // S*QW
    ushort* obf   = qbf   + (size_t)SS * QW;         // S*OW
    ushort* wqat  = obf   + (size_t)SS * OW;         // QLAT*EE  } contiguous ->
    ushort* wkvat = wqat  + (size_t)QLAT * EE;       // CKVW*EE  } merged Bt[2112][EE]
    ushort* wqbt  = wkvat + (size_t)CKVW * EE;       // QW*QLAT
    ushort* wkvbt = wqbt  + (size_t)QW * QLAT;       // KVW*KLAT
    ushort* woutt = wkvbt + (size_t)KVW * KLAT;      // EE*OW
    ushort* kf    = woutt + (size_t)EE * OW;         // HH*SS*192
    ushort* vt2   = kf    + (size_t)HH * SS * 192;   // HH*SS*DV (frag-ordered)
    float*  ml    = (float*)(vt2 + (size_t)HH * SS * DV);  // HH*32*NSEG*64*2 floats
    // overlay zone (all dead before attention writes opart):
    ushort* qac   = (ushort*)(ml + (size_t)HH * 32 * NSEG * 64 * 2);  // S*QAC
    ushort* xbf   = qac   + (size_t)SS * QAC;        // S*EE
    ushort* kvbf  = xbf   + (size_t)SS * EE;         // S*KVW
    ushort* kpebf = kvbf  + (size_t)SS * KVW;        // S*DR
    float*  rtab  = (float*)(kpebf + (size_t)SS * DR);  // SS*32*2 floats (cos,sin)
    ushort* opart = qac;  // HH*32*NSEG*64*128 halfs <= overlay span (17.04M)

    detect_dtype<<<1, 1, 0, stream>>>((const unsigned int*)q_a_ln, flag);
    rope_tab<<<SS * 32 / 256, 256, 0, stream>>>(rtab);

    conv_x_bf<<<(SS * EE / 4 + 255) / 256, 256, 0, stream>>>(x, xbf, SS * EE, flag);
    transpose5_bf<<<dim3(64, 32, 5), 256, 0, stream>>>(
        w_q_a, w_kv_a, w_q_b, w_kv_b, w_out,
        wqat, wkvat, wqbt, wkvbt, woutt, flag);

    // qac = x @ [w_q_a | w_kv_a]  (2048 x 2112, K=2048), merged, 544 blocks
    gemm_bf64<<<dim3((QAC + 127) / 128, SS / 64), 256, 0, stream>>>(
        xbf, wqat, qac, QAC, EE, EE, EE, QAC, 1, nullptr);

    rmsnorm2_bf<<<dim3(SS, 2), 256, 0, stream>>>(qac, q_a_ln, kv_a_ln, flag);

    // qbf = qa_norm @ w_q_b (2048x3072, K=1536), A = qac cols 0..1536
    gemm_bf<<<dim3(QW / 128, SS / 128), 256, 0, stream>>>(
        qac, wqbt, qbf, QW, QLAT, QAC, QLAT, QW, 1, nullptr);
    // kvbf = ckv_norm @ w_kv_b (2048x4096, K=512), A = qac cols 1536..2048
    gemm_bf<<<dim3(KVW / 128, SS / 128), 256, 0, stream>>>(
        qac + QLAT, wkvbt, kvbf, KVW, KLAT, QAC, KLAT, KVW, 1, nullptr);

    rope_apply<<<(SS * HH + SS + 255) / 256, 256, 0, stream>>>(qbf, qac, kpebf, rtab);

    build_kf<<<SS * HH * 24 / 256, 256, 0, stream>>>(kvbf, kpebf, kf);
    build_vt2<<<dim3(SS / 64, HH), 256, 0, stream>>>(kvbf, vt2);

    attn_mfma2<<<dim3(NSEG, SS / 64, HH), 256, 0, stream>>>(qbf, kf, vt2, opart, ml);
    merge_attn<<<SS, 256, 0, stream>>>(opart, ml, obf);

    // out = o @ w_out (2048x2048, K=2048), 512 blocks via 64-tile
    gemm_bf64<<<dim3(EE / 128, SS / 64), 256, 0, stream>>>(
        obf, woutt, d_out, EE, OW, OW, OW, EE, 2, flag);
}

// Round 5
// 407.715 us; speedup vs baseline: 1.3724x; 1.0064x over previous
//
#include <hip/hip_runtime.h>
#include <hip/hip_bf16.h>
#include <math.h>

// Problem constants (fixed shapes)
#define SS   2048   // sequence length
#define EE   2048   // embed dim
#define HH   16     // heads
#define QLAT 1536   // q latent
#define KLAT 512    // kv latent
#define DN   128
#define DR   64
#define DV   128
#define DQ   192    // DN+DR
#define KVD  256    // DN+DV
#define CKVW 576    // KLAT+DR
#define QW   3072   // HH*DQ
#define KVW  4096   // HH*KVD
#define OW   2048   // HH*DV
#define QAC  2112   // QLAT + CKVW (merged a-proj output width)

#define NSEG 4      // key segments (flash-decoding split)
#define PT_STRIDE 72
#define KTSZ (6 * 64 * 32)   // one K-chunk in LDS (ushorts)

typedef __attribute__((ext_vector_type(8))) short short8;
typedef __attribute__((ext_vector_type(4))) float f32x4;

// ---------------- helpers ----------------
__global__ void detect_dtype(const unsigned int* __restrict__ lnw, int* flag) {
    *flag = (lnw[0] == 0x3F803F80u) ? 1 : 0;  // bf16 pair of 1.0 vs fp32 1.0
}

__device__ __forceinline__ float ld_in(const void* p, size_t i, int bf) {
    if (bf) return __bfloat162float(((const __hip_bfloat16*)p)[i]);
    return ((const float*)p)[i];
}

__device__ __forceinline__ ushort f2b(float v) {
    __hip_bfloat16 b = __float2bfloat16(v);
    return *(ushort*)&b;
}
__device__ __forceinline__ float b2f(ushort u) {
    __hip_bfloat16 b = *(__hip_bfloat16*)&u;
    return __bfloat162float(b);
}

// async global->LDS, 16 B per lane; LDS dst must be wave-uniform base + lane*16
__device__ __forceinline__ void async16(const ushort* g, ushort* l) {
    __builtin_amdgcn_global_load_lds(
        (const __attribute__((address_space(1))) void*)g,
        (__attribute__((address_space(3))) void*)l, 16, 0, 0);
}

// ---------------- input convert (x -> bf16) ----------------
__global__ __launch_bounds__(256) void conv_x_bf(
    const void* __restrict__ src, ushort* __restrict__ dst, int n, const int* flag) {
    const int bf = *flag;
    int i = (blockIdx.x * 256 + threadIdx.x) * 4;
    if (i >= n) return;
    ushort4 u;
    u.x = f2b(ld_in(src, i + 0, bf));
    u.y = f2b(ld_in(src, i + 1, bf));
    u.z = f2b(ld_in(src, i + 2, bf));
    u.w = f2b(ld_in(src, i + 3, bf));
    *(ushort4*)(dst + i) = u;
}

// ---------------- batched weight transpose+convert: in[R][C] -> out[C][R] bf16 ----
__global__ __launch_bounds__(256) void transpose5_bf(
    const void* __restrict__ s0, const void* __restrict__ s1,
    const void* __restrict__ s2, const void* __restrict__ s3,
    const void* __restrict__ s4,
    ushort* __restrict__ d0, ushort* __restrict__ d1, ushort* __restrict__ d2,
    ushort* __restrict__ d3, ushort* __restrict__ d4,
    const int* flag) {
    const int z = blockIdx.z;
    const void* in; ushort* out; int R, C;
    switch (z) {
        case 0:  in = s0; out = d0; R = EE;   C = QLAT; break;  // w_q_a
        case 1:  in = s1; out = d1; R = EE;   C = CKVW; break;  // w_kv_a
        case 2:  in = s2; out = d2; R = QLAT; C = QW;   break;  // w_q_b
        case 3:  in = s3; out = d3; R = KLAT; C = KVW;  break;  // w_kv_b
        default: in = s4; out = d4; R = OW;   C = EE;   break;  // w_out
    }
    const int c0 = blockIdx.x * 64, r0 = blockIdx.y * 64;
    if (c0 >= C || r0 >= R) return;
    const int bf = *flag;
    __shared__ ushort t[64][66];
    const int lane = threadIdx.x & 63, grp = threadIdx.x >> 6;
    #pragma unroll
    for (int p = 0; p < 16; ++p) {
        int r = p * 4 + grp;
        t[lane][r] = f2b(ld_in(in, (size_t)(r0 + r) * C + c0 + lane, bf));
    }
    __syncthreads();
    const int ro = (threadIdx.x & 31) * 2, co = threadIdx.x >> 5;
    #pragma unroll
    for (int p = 0; p < 8; ++p) {
        int c = p * 8 + co;
        ushort2 u = *(const ushort2*)&t[c][ro];
        *(ushort2*)&out[(size_t)(c0 + c) * R + r0 + ro] = u;
    }
}

// ---------------- bf16 MFMA GEMM 128x128, 3-stage counted-vmcnt pipeline ----
// v5: the 2-stage pipeline stalled ~400-700 cyc per K-step (compute phase of
// 16 MFMA ~100-250 cyc < HBM latency ~600-900 cyc; grid-limited ~2 blocks/CU
// means TLP can't cover). 3-stage + counted vmcnt: waits for step c while
// step c+1's loads stay in flight across the barrier (T4: never drain to 0
// mid-loop); cover = 2 compute phases. Uniform load counts required for the
// counted wait: B rows are CLAMPED (not skipped) and garbage cols masked at
// the n<N C-write. cflag is read volatile BEFORE the prologue so no stray
// vmem op perturbs the counts.
__global__ __launch_bounds__(256) void gemm_bf(
    const ushort* __restrict__ A, const ushort* __restrict__ Bt,
    void* __restrict__ C, int N, int K, int lda, int ldb, int ldc,
    int cmode, const int* __restrict__ cflag) {
    __shared__ ushort As[3][128 * 32];
    __shared__ ushort Bs[3][128 * 32];
    const int tid = threadIdx.x;
    const int bm = blockIdx.y * 128, bn = blockIdx.x * 128;
    const int lane = tid & 63, wv = tid >> 6;
    const int wm = (wv & 1) * 64, wn = (wv >> 1) * 64;
    const int ln = lane & 15, quad = lane >> 4;

    int cbf = cmode;
    if (cmode == 2) cbf = *(volatile const int*)cflag;  // issued before staging loads

    f32x4 acc[4][4];
    #pragma unroll
    for (int i = 0; i < 4; ++i)
        #pragma unroll
        for (int j = 0; j < 4; ++j) acc[i][j] = (f32x4){0.f, 0.f, 0.f, 0.f};

    const int srow = tid >> 2;
    const int spart = (((tid & 3) ^ ((tid >> 3) & 3))) * 8;  // swizzled source 16B part
    const ushort* Ag0 = A  + (size_t)(bm + srow) * lda + spart;
    const ushort* Ag1 = Ag0 + (size_t)64 * lda;
    const int br0 = (bn + srow)      < N ? (bn + srow)      : (N - 1);  // clamp, not skip
    const int br1 = (bn + 64 + srow) < N ? (bn + 64 + srow) : (N - 1);
    const ushort* Bg0 = Bt + (size_t)br0 * ldb + spart;
    const ushort* Bg1 = Bt + (size_t)br1 * ldb + spart;
    const int swq = (quad ^ ((ln >> 1) & 3)) * 8;  // swizzled read part
    const int nsteps = K >> 5;   // all K here are >= 64 (nsteps >= 2)

    // prologue: stage steps 0 and 1 (8 loads in flight per wave)
    {
        ushort* Asl = As[0] + tid * 8;
        ushort* Bsl = Bs[0] + tid * 8;
        async16(Ag0, Asl);
        async16(Ag1, Asl + 2048);
        async16(Bg0, Bsl);
        async16(Bg1, Bsl + 2048);
        Asl = As[1] + tid * 8;
        Bsl = Bs[1] + tid * 8;
        async16(Ag0 + 32, Asl);
        async16(Ag1 + 32, Asl + 2048);
        async16(Bg0 + 32, Bsl);
        async16(Bg1 + 32, Bsl + 2048);
    }

    int cb = 0, ib = 2;   // compute buffer, issue buffer (= cb+2 mod 3)
    for (int c = 0; c < nsteps; ++c) {
        // wait for step c's 4 loads; keep step c+1's 4 in flight (counted)
        if (c + 1 < nsteps) asm volatile("s_waitcnt vmcnt(4)" ::: "memory");
        else                asm volatile("s_waitcnt vmcnt(0)" ::: "memory");
        __builtin_amdgcn_s_barrier();
        asm volatile("" ::: "memory");
        if (c + 2 < nsteps) {
            const int k2 = (c + 2) << 5;
            ushort* Asl = As[ib] + tid * 8;
            ushort* Bsl = Bs[ib] + tid * 8;
            async16(Ag0 + k2, Asl);
            async16(Ag1 + k2, Asl + 2048);
            async16(Bg0 + k2, Bsl);
            async16(Bg1 + k2, Bsl + 2048);
        }
        const ushort* Ac = As[cb];
        const ushort* Bc = Bs[cb];
        short8 af[4], bfr[4];
        #pragma unroll
        for (int t = 0; t < 4; ++t) {
            af[t]  = *(const short8*)&Ac[(wm + t * 16 + ln) * 32 + swq];
            bfr[t] = *(const short8*)&Bc[(wn + t * 16 + ln) * 32 + swq];
        }
        __builtin_amdgcn_s_setprio(1);
        #pragma unroll
        for (int i = 0; i < 4; ++i)
            #pragma unroll
            for (int j = 0; j < 4; ++j)
                acc[i][j] = __builtin_amdgcn_mfma_f32_16x16x32_bf16(af[i], bfr[j], acc[i][j], 0, 0, 0);
        __builtin_amdgcn_s_setprio(0);
        cb = (cb == 2) ? 0 : cb + 1;
        ib = (ib == 2) ? 0 : ib + 1;
    }

    #pragma unroll
    for (int i = 0; i < 4; ++i) {
        #pragma unroll
        for (int r = 0; r < 4; ++r) {
            const int m = bm + wm + i * 16 + quad * 4 + r;
            #pragma unroll
            for (int j = 0; j < 4; ++j) {
                const int n = bn + wn + j * 16 + ln;
                if (n < N) {
                    if (cbf) ((ushort*)C)[(size_t)m * ldc + n] = f2b(acc[i][j][r]);
                    else     ((float*)C)[(size_t)m * ldc + n] = acc[i][j][r];
                }
            }
        }
    }
}

// ---------------- bf16 MFMA GEMM 64x128, 3-stage counted-vmcnt pipeline ----
__global__ __launch_bounds__(256) void gemm_bf64(
    const ushort* __restrict__ A, const ushort* __restrict__ Bt,
    void* __restrict__ C, int N, int K, int lda, int ldb, int ldc,
    int cmode, const int* __restrict__ cflag) {
    __shared__ ushort As[3][64 * 32];
    __shared__ ushort Bs[3][128 * 32];
    const int tid = threadIdx.x;
    const int bm = blockIdx.y * 64, bn = blockIdx.x * 128;
    const int lane = tid & 63, wv = tid >> 6;
    const int wm = (wv & 1) * 32, wn = (wv >> 1) * 64;
    const int ln = lane & 15, quad = lane >> 4;

    int cbf = cmode;
    if (cmode == 2) cbf = *(volatile const int*)cflag;  // issued before staging loads

    f32x4 acc[2][4];
    #pragma unroll
    for (int i = 0; i < 2; ++i)
        #pragma unroll
        for (int j = 0; j < 4; ++j) acc[i][j] = (f32x4){0.f, 0.f, 0.f, 0.f};

    const int srow = tid >> 2;
    const int spart = (((tid & 3) ^ ((tid >> 3) & 3))) * 8;
    const ushort* Ag0 = A  + (size_t)(bm + srow) * lda + spart;
    const int br0 = (bn + srow)      < N ? (bn + srow)      : (N - 1);
    const int br1 = (bn + 64 + srow) < N ? (bn + 64 + srow) : (N - 1);
    const ushort* Bg0 = Bt + (size_t)br0 * ldb + spart;
    const ushort* Bg1 = Bt + (size_t)br1 * ldb + spart;
    const int swq = (quad ^ ((ln >> 1) & 3)) * 8;
    const int nsteps = K >> 5;

    // prologue: stage steps 0 and 1 (6 loads in flight per wave)
    {
        ushort* Asl = As[0] + tid * 8;
        ushort* Bsl = Bs[0] + tid * 8;
        async16(Ag0, Asl);
        async16(Bg0, Bsl);
        async16(Bg1, Bsl + 2048);
        Asl = As[1] + tid * 8;
        Bsl = Bs[1] + tid * 8;
        async16(Ag0 + 32, Asl);
        async16(Bg0 + 32, Bsl);
        async16(Bg1 + 32, Bsl + 2048);
    }

    int cb = 0, ib = 2;
    for (int c = 0; c < nsteps; ++c) {
        if (c + 1 < nsteps) asm volatile("s_waitcnt vmcnt(3)" ::: "memory");
        else                asm volatile("s_waitcnt vmcnt(0)" ::: "memory");
        __builtin_amdgcn_s_barrier();
        asm volatile("" ::: "memory");
        if (c + 2 < nsteps) {
            const int k2 = (c + 2) << 5;
            ushort* Asl = As[ib] + tid * 8;
            ushort* Bsl = Bs[ib] + tid * 8;
            async16(Ag0 + k2, Asl);
            async16(Bg0 + k2, Bsl);
            async16(Bg1 + k2, Bsl + 2048);
        }
        const ushort* Ac = As[cb];
        const ushort* Bc = Bs[cb];
        short8 af[2], bfr[4];
        #pragma unroll
        for (int t = 0; t < 2; ++t)
            af[t] = *(const short8*)&Ac[(wm + t * 16 + ln) * 32 + swq];
        #pragma unroll
        for (int t = 0; t < 4; ++t)
            bfr[t] = *(const short8*)&Bc[(wn + t * 16 + ln) * 32 + swq];
        __builtin_amdgcn_s_setprio(1);
        #pragma unroll
        for (int i = 0; i < 2; ++i)
            #pragma unroll
            for (int j = 0; j < 4; ++j)
                acc[i][j] = __builtin_amdgcn_mfma_f32_16x16x32_bf16(af[i], bfr[j], acc[i][j], 0, 0, 0);
        __builtin_amdgcn_s_setprio(0);
        cb = (cb == 2) ? 0 : cb + 1;
        ib = (ib == 2) ? 0 : ib + 1;
    }

    #pragma unroll
    for (int i = 0; i < 2; ++i) {
        #pragma unroll
        for (int r = 0; r < 4; ++r) {
            const int m = bm + wm + i * 16 + quad * 4 + r;
            #pragma unroll
            for (int j = 0; j < 4; ++j) {
                const int n = bn + wn + j * 16 + ln;
                if (n < N) {
                    if (cbf) ((ushort*)C)[(size_t)m * ldc + n] = f2b(acc[i][j][r]);
                    else     ((float*)C)[(size_t)m * ldc + n] = acc[i][j][r];
                }
            }
        }
    }
}

// ---------------- RMSNorm bf16 in-place (fp32 math), both norms fused ------
__global__ __launch_bounds__(256) void rmsnorm2_bf(
    ushort* __restrict__ x, const void* __restrict__ wq,
    const void* __restrict__ wkv, const int* wflag) {
    const int wbf = *wflag;
    const int which = blockIdx.y;
    const int cols = which ? KLAT : QLAT;
    const void* w = which ? wkv : wq;
    ushort* p = x + (size_t)blockIdx.x * QAC + (which ? QLAT : 0);
    float ss = 0.f;
    for (int i = threadIdx.x; i < cols; i += 256) { float v = b2f(p[i]); ss += v * v; }
    #pragma unroll
    for (int off = 32; off; off >>= 1) ss += __shfl_xor(ss, off);
    __shared__ float red[4];
    const int wid = threadIdx.x >> 6, lane = threadIdx.x & 63;
    if (lane == 0) red[wid] = ss;
    __syncthreads();
    const float tot = red[0] + red[1] + red[2] + red[3];
    const float scale = rsqrtf(tot / (float)cols + 1e-6f);
    for (int i = threadIdx.x; i < cols; i += 256)
        p[i] = f2b(b2f(p[i]) * scale * ld_in(w, i, wbf));
}

// ---------------- RoPE: table + vectorized apply ----------------------------
__global__ __launch_bounds__(256) void rope_tab(float* __restrict__ tab) {
    int idx = blockIdx.x * 256 + threadIdx.x;   // SS*32
    int s = idx >> 5, i = idx & 31;
    float inv = powf(10000.0f, -(float)i / 32.0f);
    float sv, cv;
    sincosf((float)s * inv, &sv, &cv);
    tab[idx * 2]     = cv;
    tab[idx * 2 + 1] = sv;
}

__device__ __forceinline__ void rope_block(
    const ushort* __restrict__ src, ushort* __restrict__ dst,
    const float* __restrict__ tb) {
    short8 vin[8];
    #pragma unroll
    for (int t = 0; t < 8; ++t) vin[t] = *(const short8*)(src + t * 8);
    short8 lo[4], hi[4];
    #pragma unroll
    for (int t = 0; t < 4; ++t) {
        #pragma unroll
        for (int j = 0; j < 8; ++j) {
            const int i = t * 8 + j;
            float cv = tb[2 * i], sv = tb[2 * i + 1];
            ushort u0 = ((const ushort*)&vin[(2 * i) >> 3])[(2 * i) & 7];
            ushort u1 = ((const ushort*)&vin[(2 * i + 1) >> 3])[(2 * i + 1) & 7];
            float x0 = b2f(u0), x1 = b2f(u1);
            lo[t][j] = (short)f2b(x0 * cv - x1 * sv);
            hi[t][j] = (short)f2b(x1 * cv + x0 * sv);
        }
    }
    #pragma unroll
    for (int t = 0; t < 4; ++t) {
        *(short8*)(dst + t * 8)      = lo[t];
        *(short8*)(dst + 32 + t * 8) = hi[t];
    }
}

__global__ __launch_bounds__(256) void rope_apply(
    ushort* __restrict__ q, const ushort* __restrict__ qac,
    ushort* __restrict__ kpe, const float* __restrict__ tab) {
    int idx = blockIdx.x * blockDim.x + threadIdx.x;
    if (idx < SS * HH) {
        int s = idx >> 4, h = idx & 15;
        ushort* p = q + (size_t)s * QW + h * DQ + DN;
        rope_block(p, p, tab + s * 64);
    } else if (idx < SS * HH + SS) {
        int s = idx - SS * HH;
        rope_block(qac + (size_t)s * QAC + QLAT + KLAT,
                   kpe + (size_t)s * DR, tab + s * 64);
    }
}

// ---------------- build head-major K-full: kf[h][s][192] ----------------
__global__ __launch_bounds__(256) void build_kf(
    const ushort* __restrict__ kv, const ushort* __restrict__ kpe,
    ushort* __restrict__ kf) {
    int idx = blockIdx.x * 256 + threadIdx.x;       // SS*HH*24 items
    int part = idx % 24;
    int rest = idx / 24;
    int h = rest & 15, s = rest >> 4;
    short8 v;
    if (part < 16) v = *(const short8*)(kv + (size_t)s * KVW + h * KVD + part * 8);
    else           v = *(const short8*)(kpe + (size_t)s * DR + (part - 16) * 8);
    *(short8*)(kf + ((size_t)h * SS + s) * 192 + part * 8) = v;
}

// ---------------- build frag-ordered V: vt2[h][ck][idx2=kb2*8+nb][lane][8] ----------------
__global__ __launch_bounds__(256) void build_vt2(
    const ushort* __restrict__ kv, ushort* __restrict__ vt2) {
    __shared__ ushort Vl[64 * 136];
    const int ck = blockIdx.x, h = blockIdx.y;
    const int tid = threadIdx.x;
    const int lane = tid & 63, wv = tid >> 6;
    #pragma unroll
    for (int rr = 0; rr < 4; ++rr) {
        int n = rr * 256 + tid;
        int key = n >> 4, part = n & 15;
        short8 v = *(const short8*)(kv + (size_t)(ck * 64 + key) * KVW + h * KVD + DN + part * 8);
        *(short8*)&Vl[key * 136 + part * 8] = v;
    }
    __syncthreads();
    const int ln = lane & 15, quad = lane >> 4;
    ushort* dst = vt2 + (((size_t)h * 32 + ck) * 16) * 512;
    #pragma unroll
    for (int w = 0; w < 4; ++w) {
        int idx2 = wv * 4 + w;
        int kb2 = idx2 >> 3, nb = idx2 & 7;
        short8 v;
        #pragma unroll
        for (int j = 0; j < 8; ++j)
            ((ushort*)&v)[j] = Vl[(kb2 * 32 + quad * 8 + j) * 136 + nb * 16 + ln];
        *(short8*)(dst + (size_t)idx2 * 512 + lane * 8) = v;
    }
}

// ---------------- split-K MFMA flash attention (unchanged) ----------
__global__ __launch_bounds__(256, 2) void attn_mfma2(
    const ushort* __restrict__ qbf, const ushort* __restrict__ kf,
    const ushort* __restrict__ vt2, ushort* __restrict__ opart,
    float* __restrict__ ml) {
    const int seg = blockIdx.x, bq = 31 - blockIdx.y, h = blockIdx.z;
    const int ctot = bq + 1;
    const int c_lo = (seg * ctot) >> 2;
    const int nch = (((seg + 1) * ctot) >> 2) - c_lo;
    if (nch <= 0) return;

    __shared__ ushort Kt[2 * KTSZ];              // 2 x 24576 B
    __shared__ ushort Pt[4][16 * PT_STRIDE];     // 9216 B

    const int tid = threadIdx.x, lane = tid & 63, wl = tid >> 6;
    const int ln = lane & 15, quad = lane >> 4;
    const int qw = bq * 64 + wl * 16;
    const int kstart = c_lo << 6;
    const float scale = 0.07216878364870322f;  // 1/sqrt(192)

    short8 aq[6];
    const ushort* qrow = qbf + (size_t)(qw + ln) * QW + h * DQ;
    #pragma unroll
    for (int kb = 0; kb < 6; ++kb)
        aq[kb] = *(const short8*)(qrow + kb * 32 + quad * 8);

    const ushort* kfh = kf + (size_t)h * SS * 192;
    const ushort* vth2 = vt2 + ((size_t)h * 32 * 16) * 512 + lane * 8;

    const int key_s = tid >> 2;
    const int swp = ((tid & 3) ^ ((tid >> 3) & 3)) * 8;
    const ushort* kg = kfh + (size_t)(kstart + key_s) * 192 + swp;
    const int swq = (quad ^ ((ln >> 1) & 3)) * 8;

    f32x4 oacc[8];
    #pragma unroll
    for (int f = 0; f < 8; ++f) oacc[f] = (f32x4){0.f, 0.f, 0.f, 0.f};
    float mrow[4] = {-INFINITY, -INFINITY, -INFINITY, -INFINITY};
    float lrow[4] = {0.f, 0.f, 0.f, 0.f};

    {
        ushort* kd = Kt + tid * 8;
        #pragma unroll
        for (int i = 0; i < 6; ++i)
            async16(kg + i * 32, kd + i * 2048);
        kg += (size_t)64 * 192;
    }

    for (int c = 0; c < nch; ++c) {
        const int k0 = kstart + (c << 6);
        asm volatile("s_waitcnt vmcnt(0)" ::: "memory");
        __builtin_amdgcn_s_barrier();
        asm volatile("" ::: "memory");
        if (c + 1 < nch) {
            ushort* kd = Kt + ((c + 1) & 1) * KTSZ + tid * 8;
            #pragma unroll
            for (int i = 0; i < 6; ++i)
                async16(kg + i * 32, kd + i * 2048);
            kg += (size_t)64 * 192;
        }
        const ushort* Kcur = Kt + (c & 1) * KTSZ;

        const ushort* vfr = vth2 + (size_t)(k0 >> 6) * 16 * 512;
        short8 bv0[8];
        #pragma unroll
        for (int nb = 0; nb < 8; ++nb)
            bv0[nb] = *(const short8*)(vfr + (size_t)nb * 512);
        f32x4 s[4];
        #pragma unroll
        for (int ns = 0; ns < 4; ++ns) s[ns] = (f32x4){0.f, 0.f, 0.f, 0.f};
        __builtin_amdgcn_s_setprio(1);
        #pragma unroll
        for (int ns = 0; ns < 4; ++ns)
            #pragma unroll
            for (int kb = 0; kb < 6; ++kb) {
                short8 bk = *(const short8*)&Kcur[(kb * 64 + ns * 16 + ln) * 32 + swq];
                s[ns] = __builtin_amdgcn_mfma_f32_16x16x32_bf16(aq[kb], bk, s[ns], 0, 0, 0);
            }
        __builtin_amdgcn_s_setprio(0);
        float pv[4][4], rmax[4];
        #pragma unroll
        for (int r = 0; r < 4; ++r) rmax[r] = -1e30f;
        #pragma unroll
        for (int ns = 0; ns < 4; ++ns)
            #pragma unroll
            for (int r = 0; r < 4; ++r) {
                int key = k0 + ns * 16 + ln;
                int qr = qw + quad * 4 + r;
                float v = s[ns][r] * scale;
                if (key > qr) v = -1e30f;
                pv[ns][r] = v;
                rmax[r] = fmaxf(rmax[r], v);
            }
        #pragma unroll
        for (int off = 8; off; off >>= 1)
            #pragma unroll
            for (int r = 0; r < 4; ++r)
                rmax[r] = fmaxf(rmax[r], __shfl_xor(rmax[r], off));
        float alpha[4], psum[4];
        #pragma unroll
        for (int r = 0; r < 4; ++r) {
            float mnew = fmaxf(mrow[r], rmax[r]);
            alpha[r] = __expf(mrow[r] - mnew);
            mrow[r] = mnew;
        }
        #pragma unroll
        for (int ns = 0; ns < 4; ++ns)
            #pragma unroll
            for (int r = 0; r < 4; ++r)
                pv[ns][r] = __expf(pv[ns][r] - mrow[r]);
        #pragma unroll
        for (int r = 0; r < 4; ++r)
            psum[r] = (pv[0][r] + pv[1][r]) + (pv[2][r] + pv[3][r]);
        #pragma unroll
        for (int off = 8; off; off >>= 1)
            #pragma unroll
            for (int r = 0; r < 4; ++r)
                psum[r] += __shfl_xor(psum[r], off);
        #pragma unroll
        for (int r = 0; r < 4; ++r) lrow[r] = lrow[r] * alpha[r] + psum[r];
        #pragma unroll
        for (int f = 0; f < 8; ++f)
            #pragma unroll
            for (int r = 0; r < 4; ++r) oacc[f][r] *= alpha[r];
        #pragma unroll
        for (int ns = 0; ns < 4; ++ns)
            #pragma unroll
            for (int r = 0; r < 4; ++r)
                Pt[wl][(quad * 4 + r) * PT_STRIDE + ns * 16 + ln] = f2b(pv[ns][r]);
        short8 bv1[8];
        #pragma unroll
        for (int nb = 0; nb < 8; ++nb)
            bv1[nb] = *(const short8*)(vfr + (size_t)(8 + nb) * 512);
        short8 pa0 = *(const short8*)&Pt[wl][ln * PT_STRIDE + quad * 8];
        short8 pa1 = *(const short8*)&Pt[wl][ln * PT_STRIDE + 32 + quad * 8];
        __builtin_amdgcn_s_setprio(1);
        #pragma unroll
        for (int nb = 0; nb < 8; ++nb)
            oacc[nb] = __builtin_amdgcn_mfma_f32_16x16x32_bf16(pa0, bv0[nb], oacc[nb], 0, 0, 0);
        #pragma unroll
        for (int nb = 0; nb < 8; ++nb)
            oacc[nb] = __builtin_amdgcn_mfma_f32_16x16x32_bf16(pa1, bv1[nb], oacc[nb], 0, 0, 0);
        __builtin_amdgcn_s_setprio(0);
    }

    const size_t pbase = (((size_t)h * 32 + bq) * NSEG + seg) * 64;
    #pragma unroll
    for (int nb = 0; nb < 8; ++nb)
        #pragma unroll
        for (int r = 0; r < 4; ++r)
            opart[(pbase + wl * 16 + quad * 4 + r) * 128 + nb * 16 + ln] = f2b(oacc[nb][r]);
    if (ln == 0) {
        #pragma unroll
        for (int r = 0; r < 4; ++r) {
            ml[(pbase + wl * 16 + quad * 4 + r) * 2]     = mrow[r];
            ml[(pbase + wl * 16 + quad * 4 + r) * 2 + 1] = lrow[r];
        }
    }
}

// ---------------- merge partials -> obf ----------------
__global__ __launch_bounds__(256) void merge_attn(
    const ushort* __restrict__ opart, const float* __restrict__ ml,
    ushort* __restrict__ obf) {
    const int q = blockIdx.x;
    const int bq = q >> 6, row = q & 63;
    const int ctot = bq + 1;
    const int t = threadIdx.x;
    #pragma unroll
    for (int pp = 0; pp < 8; ++pp) {
        int idx = pp * 256 + t;            // 0..2047 = h*128 + d
        int h = idx >> 7, d = idx & 127;
        size_t rbase = (((size_t)h * 32 + bq) * NSEG) * 64 + row;  // + s*64
        float M = -1e30f;
        #pragma unroll
        for (int s = 0; s < NSEG; ++s) {
            if ((((s + 1) * ctot) >> 2) > ((s * ctot) >> 2))
                M = fmaxf(M, ml[(rbase + (size_t)s * 64) * 2]);
        }
        float L = 0.f, acc = 0.f;
        #pragma unroll
        for (int s = 0; s < NSEG; ++s) {
            if ((((s + 1) * ctot) >> 2) > ((s * ctot) >> 2)) {
                size_t ri = rbase + (size_t)s * 64;
                float w = __expf(ml[ri * 2] - M);
                L += w * ml[ri * 2 + 1];
                acc += w * b2f(opart[ri * 128 + d]);
            }
        }
        obf[(size_t)q * OW + h * DV + d] = f2b(acc / L);
    }
}

// ---------------- launch ----------------
extern "C" void kernel_launch(void* const* d_in, const int* in_sizes, int n_in,
                              void* d_out, int out_size, void* d_ws, size_t ws_size,
                              hipStream_t stream) {
    const void* x       = d_in[0];
    const void* w_q_a   = d_in[1];
    const void* q_a_ln  = d_in[2];
    const void* w_q_b   = d_in[3];
    const void* w_kv_a  = d_in[4];
    const void* kv_a_ln = d_in[5];
    const void* w_kv_b  = d_in[6];
    const void* w_out   = d_in[7];

    char* ws = (char*)d_ws;
    int*    flag  = (int*)ws;
    ushort* qbf   = (ushort*)(ws + 256);             // S*QW
    ushort* obf   = qbf   + (size_t)SS * QW;         // S*OW
    ushort* wqat  = obf   + (size_t)SS * OW;         // QLAT*EE  } contiguous ->
    ushort* wkvat = wqat  + (size_t)QLAT * EE;       // CKVW*EE  } merged Bt[2112][EE]
    ushort* wqbt  = wkvat + (size_t)CKVW * EE;       // QW*QLAT
    ushort* wkvbt = wqbt  + (size_t)QW * QLAT;       // KVW*KLAT
    ushort* woutt = wkvbt + (size_t)KVW * KLAT;      // EE*OW
    ushort* kf    = woutt + (size_t)EE * OW;         // HH*SS*192
    ushort* vt2   = kf    + (size_t)HH * SS * 192;   // HH*SS*DV (frag-ordered)
    float*  ml    = (float*)(vt2 + (size_t)HH * SS * DV);  // HH*32*NSEG*64*2 floats
    // overlay zone (all dead before attention writes opart):
    ushort* qac   = (ushort*)(ml + (size_t)HH * 32 * NSEG * 64 * 2);  // S*QAC
    ushort* xbf   = qac   + (size_t)SS * QAC;        // S*EE
    ushort* kvbf  = xbf   + (size_t)SS * EE;         // S*KVW
    ushort* kpebf = kvbf  + (size_t)SS * KVW;        // S*DR
    float*  rtab  = (float*)(kpebf + (size_t)SS * DR);  // SS*32*2 floats (cos,sin)
    ushort* opart = qac;  // HH*32*NSEG*64*128 halfs <= overlay span (17.04M)

    detect_dtype<<<1, 1, 0, stream>>>((const unsigned int*)q_a_ln, flag);
    rope_tab<<<SS * 32 / 256, 256, 0, stream>>>(rtab);

    conv_x_bf<<<(SS * EE / 4 + 255) / 256, 256, 0, stream>>>(x, xbf, SS * EE, flag);
    transpose5_bf<<<dim3(64, 32, 5), 256, 0, stream>>>(
        w_q_a, w_kv_a, w_q_b, w_kv_b, w_out,
        wqat, wkvat, wqbt, wkvbt, woutt, flag);

    // qac = x @ [w_q_a | w_kv_a]  (2048 x 2112, K=2048), merged, 544 blocks
    gemm_bf64<<<dim3((QAC + 127) / 128, SS / 64), 256, 0, stream>>>(
        xbf, wqat, qac, QAC, EE, EE, EE, QAC, 1, nullptr);

    rmsnorm2_bf<<<dim3(SS, 2), 256, 0, stream>>>(qac, q_a_ln, kv_a_ln, flag);

    // qbf = qa_norm @ w_q_b (2048x3072, K=1536), A = qac cols 0..1536
    gemm_bf<<<dim3(QW / 128, SS / 128), 256, 0, stream>>>(
        qac, wqbt, qbf, QW, QLAT, QAC, QLAT, QW, 1, nullptr);
    // kvbf = ckv_norm @ w_kv_b (2048x4096, K=512), A = qac cols 1536..2048
    gemm_bf<<<dim3(KVW / 128, SS / 128), 256, 0, stream>>>(
        qac + QLAT, wkvbt, kvbf, KVW, KLAT, QAC, KLAT, KVW, 1, nullptr);

    rope_apply<<<(SS * HH + SS + 255) / 256, 256, 0, stream>>>(qbf, qac, kpebf, rtab);

    build_kf<<<SS * HH * 24 / 256, 256, 0, stream>>>(kvbf, kpebf, kf);
    build_vt2<<<dim3(SS / 64, HH), 256, 0, stream>>>(kvbf, vt2);

    attn_mfma2<<<dim3(NSEG, SS / 64, HH), 256, 0, stream>>>(qbf, kf, vt2, opart, ml);
    merge_attn<<<SS, 256, 0, stream>>>(opart, ml, obf);

    // out = o @ w_out (2048x2048, K=2048), 512 blocks via 64-tile
    gemm_bf64<<<dim3(EE / 128, SS / 64), 256, 0, stream>>>(
        obf, woutt, d_out, EE, OW, OW, OW, EE, 2, flag);
}

// Round 6
// 372.192 us; speedup vs baseline: 1.5034x; 1.0954x over previous
//
#include <hip/hip_runtime.h>
#include <hip/hip_bf16.h>
#include <math.h>

// Problem constants (fixed shapes)
#define SS   2048   // sequence length
#define EE   2048   // embed dim
#define HH   16     // heads
#define QLAT 1536   // q latent
#define KLAT 512    // kv latent
#define DN   128
#define DR   64
#define DV   128
#define DQ   192    // DN+DR
#define KVD  256    // DN+DV
#define CKVW 576    // KLAT+DR
#define QW   3072   // HH*DQ
#define KVW  4096   // HH*KVD
#define OW   2048   // HH*DV
#define QAC  2112   // QLAT + CKVW (merged a-proj output width)

#define NSEG 4      // key segments (flash-decoding split)
#define PT_STRIDE 72
#define KTSZ (6 * 64 * 32)   // one K-chunk in LDS (ushorts)

typedef __attribute__((ext_vector_type(8))) short short8;
typedef __attribute__((ext_vector_type(4))) float f32x4;

// ---------------- helpers ----------------
__global__ void detect_dtype(const unsigned int* __restrict__ lnw, int* flag) {
    *flag = (lnw[0] == 0x3F803F80u) ? 1 : 0;  // bf16 pair of 1.0 vs fp32 1.0
}

__device__ __forceinline__ float ld_in(const void* p, size_t i, int bf) {
    if (bf) return __bfloat162float(((const __hip_bfloat16*)p)[i]);
    return ((const float*)p)[i];
}

__device__ __forceinline__ ushort f2b(float v) {
    __hip_bfloat16 b = __float2bfloat16(v);
    return *(ushort*)&b;
}
__device__ __forceinline__ float b2f(ushort u) {
    __hip_bfloat16 b = *(__hip_bfloat16*)&u;
    return __bfloat162float(b);
}

// async global->LDS, 16 B per lane; LDS dst must be wave-uniform base + lane*16
__device__ __forceinline__ void async16(const ushort* g, ushort* l) {
    __builtin_amdgcn_global_load_lds(
        (const __attribute__((address_space(1))) void*)g,
        (__attribute__((address_space(3))) void*)l, 16, 0, 0);
}

// ---------------- input convert (x -> bf16) ----------------
__global__ __launch_bounds__(256) void conv_x_bf(
    const void* __restrict__ src, ushort* __restrict__ dst, int n, const int* flag) {
    const int bf = *flag;
    int i = (blockIdx.x * 256 + threadIdx.x) * 4;
    if (i >= n) return;
    ushort4 u;
    u.x = f2b(ld_in(src, i + 0, bf));
    u.y = f2b(ld_in(src, i + 1, bf));
    u.z = f2b(ld_in(src, i + 2, bf));
    u.w = f2b(ld_in(src, i + 3, bf));
    *(ushort4*)(dst + i) = u;
}

// ---------------- batched weight transpose+convert: in[R][C] -> out[C][R] bf16 ----
__global__ __launch_bounds__(256) void transpose5_bf(
    const void* __restrict__ s0, const void* __restrict__ s1,
    const void* __restrict__ s2, const void* __restrict__ s3,
    const void* __restrict__ s4,
    ushort* __restrict__ d0, ushort* __restrict__ d1, ushort* __restrict__ d2,
    ushort* __restrict__ d3, ushort* __restrict__ d4,
    const int* flag) {
    const int z = blockIdx.z;
    const void* in; ushort* out; int R, C;
    switch (z) {
        case 0:  in = s0; out = d0; R = EE;   C = QLAT; break;  // w_q_a
        case 1:  in = s1; out = d1; R = EE;   C = CKVW; break;  // w_kv_a
        case 2:  in = s2; out = d2; R = QLAT; C = QW;   break;  // w_q_b
        case 3:  in = s3; out = d3; R = KLAT; C = KVW;  break;  // w_kv_b
        default: in = s4; out = d4; R = OW;   C = EE;   break;  // w_out
    }
    const int c0 = blockIdx.x * 64, r0 = blockIdx.y * 64;
    if (c0 >= C || r0 >= R) return;
    const int bf = *flag;
    __shared__ ushort t[64][66];
    const int lane = threadIdx.x & 63, grp = threadIdx.x >> 6;
    #pragma unroll
    for (int p = 0; p < 16; ++p) {
        int r = p * 4 + grp;
        t[lane][r] = f2b(ld_in(in, (size_t)(r0 + r) * C + c0 + lane, bf));
    }
    __syncthreads();
    const int ro = (threadIdx.x & 31) * 2, co = threadIdx.x >> 5;
    #pragma unroll
    for (int p = 0; p < 8; ++p) {
        int c = p * 8 + co;
        ushort2 u = *(const ushort2*)&t[c][ro];
        *(ushort2*)&out[(size_t)(c0 + c) * R + r0 + ro] = u;
    }
}

// ---------------- bf16 MFMA GEMM 128x128 body, BK=64 double-buffered --------
// v6: rounds 3/5 showed the GEMMs are NOT fetch-latency-bound (2-phase cover
// changed nothing vs 1-phase). Remaining per-step cost is barrier+stage+vmcnt
// overhead, paid per K-step -> BK 32->64 halves it. 8-slot XOR swizzle
// part' = part ^ (row&7) for the 128B rows (row*128 == 0 mod banks, so the
// swizzle must cover all 8 16B slots; 64 lanes/8 slots = bandwidth-floor).
__device__ __forceinline__ void gemm128_body(
    const ushort* __restrict__ A, const ushort* __restrict__ Bt,
    void* __restrict__ C, int N, int K, int lda, int ldb, int ldc,
    int cbf, int bm, int bn, ushort* As, ushort* Bs) {
    const int tid = threadIdx.x;
    const int lane = tid & 63, wv = tid >> 6;
    const int wm = (wv & 1) * 64, wn = (wv >> 1) * 64;
    const int ln = lane & 15, quad = lane >> 4;

    f32x4 acc[4][4];
    #pragma unroll
    for (int i = 0; i < 4; ++i)
        #pragma unroll
        for (int j = 0; j < 4; ++j) acc[i][j] = (f32x4){0.f, 0.f, 0.f, 0.f};

    const int srow = tid >> 3;                       // 0..31
    const int spart = ((tid & 7) ^ ((tid >> 3) & 7)) * 8;  // swizzled src 16B part
    const ushort* Ag0 = A + (size_t)(bm + srow) * lda + spart;
    const ushort* Ag1 = Ag0 + (size_t)32 * lda;
    const ushort* Ag2 = Ag0 + (size_t)64 * lda;
    const ushort* Ag3 = Ag0 + (size_t)96 * lda;
    const int br0 = (bn + srow)      < N ? (bn + srow)      : (N - 1);
    const int br1 = (bn + 32 + srow) < N ? (bn + 32 + srow) : (N - 1);
    const int br2 = (bn + 64 + srow) < N ? (bn + 64 + srow) : (N - 1);
    const int br3 = (bn + 96 + srow) < N ? (bn + 96 + srow) : (N - 1);
    const ushort* Bg0 = Bt + (size_t)br0 * ldb + spart;
    const ushort* Bg1 = Bt + (size_t)br1 * ldb + spart;
    const ushort* Bg2 = Bt + (size_t)br2 * ldb + spart;
    const ushort* Bg3 = Bt + (size_t)br3 * ldb + spart;
    const int nsteps = K >> 6;

    // prologue: stage step 0 into buffer 0
    {
        ushort* as = As + tid * 8;
        ushort* bs = Bs + tid * 8;
        async16(Ag0, as);          async16(Ag1, as + 2048);
        async16(Ag2, as + 4096);   async16(Ag3, as + 6144);
        async16(Bg0, bs);          async16(Bg1, bs + 2048);
        async16(Bg2, bs + 4096);   async16(Bg3, bs + 6144);
    }

    int cb = 0;
    for (int c = 0; c < nsteps; ++c) {
        asm volatile("s_waitcnt vmcnt(0)" ::: "memory");
        __builtin_amdgcn_s_barrier();
        asm volatile("" ::: "memory");
        if (c + 1 < nsteps) {
            const int k1 = (c + 1) << 6;
            ushort* as = As + (cb ^ 1) * 8192 + tid * 8;
            ushort* bs = Bs + (cb ^ 1) * 8192 + tid * 8;
            async16(Ag0 + k1, as);          async16(Ag1 + k1, as + 2048);
            async16(Ag2 + k1, as + 4096);   async16(Ag3 + k1, as + 6144);
            async16(Bg0 + k1, bs);          async16(Bg1 + k1, bs + 2048);
            async16(Bg2 + k1, bs + 4096);   async16(Bg3 + k1, bs + 6144);
        }
        const ushort* Ac = As + cb * 8192;
        const ushort* Bc = Bs + cb * 8192;
        #pragma unroll
        for (int ks = 0; ks < 2; ++ks) {
            const int sw = ((ks * 4 + quad) ^ (ln & 7)) * 8;
            short8 af[4], bfr[4];
            #pragma unroll
            for (int t = 0; t < 4; ++t) {
                af[t]  = *(const short8*)&Ac[(wm + t * 16 + ln) * 64 + sw];
                bfr[t] = *(const short8*)&Bc[(wn + t * 16 + ln) * 64 + sw];
            }
            __builtin_amdgcn_s_setprio(1);
            #pragma unroll
            for (int i = 0; i < 4; ++i)
                #pragma unroll
                for (int j = 0; j < 4; ++j)
                    acc[i][j] = __builtin_amdgcn_mfma_f32_16x16x32_bf16(af[i], bfr[j], acc[i][j], 0, 0, 0);
            __builtin_amdgcn_s_setprio(0);
        }
        cb ^= 1;
    }

    #pragma unroll
    for (int i = 0; i < 4; ++i) {
        #pragma unroll
        for (int r = 0; r < 4; ++r) {
            const int m = bm + wm + i * 16 + quad * 4 + r;
            #pragma unroll
            for (int j = 0; j < 4; ++j) {
                const int n = bn + wn + j * 16 + ln;
                if (n < N) {
                    if (cbf) ((ushort*)C)[(size_t)m * ldc + n] = f2b(acc[i][j][r]);
                    else     ((float*)C)[(size_t)m * ldc + n] = acc[i][j][r];
                }
            }
        }
    }
}

// merged q_b + kv_b GEMMs: z selects; 896 useful blocks run concurrently
__global__ __launch_bounds__(256) void gemm_qkv(
    const ushort* __restrict__ qac, const ushort* __restrict__ wqbt,
    const ushort* __restrict__ wkvbt, ushort* __restrict__ qbf_,
    ushort* __restrict__ kvbf_) {
    __shared__ ushort As[2 * 8192];
    __shared__ ushort Bs[2 * 8192];
    if (blockIdx.z == 0) {
        if (blockIdx.x >= QW / 128) return;
        gemm128_body(qac, wqbt, qbf_, QW, QLAT, QAC, QLAT, QW, 1,
                     blockIdx.y * 128, blockIdx.x * 128, As, Bs);
    } else {
        gemm128_body(qac + QLAT, wkvbt, kvbf_, KVW, KLAT, QAC, KLAT, KVW, 1,
                     blockIdx.y * 128, blockIdx.x * 128, As, Bs);
    }
}

// ---------------- bf16 MFMA GEMM 64x128, BK=64 double-buffered --------------
__global__ __launch_bounds__(256) void gemm_bf64(
    const ushort* __restrict__ A, const ushort* __restrict__ Bt,
    void* __restrict__ C, int N, int K, int lda, int ldb, int ldc,
    int cmode, const int* __restrict__ cflag) {
    __shared__ ushort As[2 * 4096];
    __shared__ ushort Bs[2 * 8192];
    const int tid = threadIdx.x;
    const int bm = blockIdx.y * 64, bn = blockIdx.x * 128;
    const int lane = tid & 63, wv = tid >> 6;
    const int wm = (wv & 1) * 32, wn = (wv >> 1) * 64;
    const int ln = lane & 15, quad = lane >> 4;

    int cbf = cmode;
    if (cmode == 2) cbf = *(volatile const int*)cflag;  // before staging loads

    f32x4 acc[2][4];
    #pragma unroll
    for (int i = 0; i < 2; ++i)
        #pragma unroll
        for (int j = 0; j < 4; ++j) acc[i][j] = (f32x4){0.f, 0.f, 0.f, 0.f};

    const int srow = tid >> 3;
    const int spart = ((tid & 7) ^ ((tid >> 3) & 7)) * 8;
    const ushort* Ag0 = A + (size_t)(bm + srow) * lda + spart;
    const ushort* Ag1 = Ag0 + (size_t)32 * lda;
    const int br0 = (bn + srow)      < N ? (bn + srow)      : (N - 1);
    const int br1 = (bn + 32 + srow) < N ? (bn + 32 + srow) : (N - 1);
    const int br2 = (bn + 64 + srow) < N ? (bn + 64 + srow) : (N - 1);
    const int br3 = (bn + 96 + srow) < N ? (bn + 96 + srow) : (N - 1);
    const ushort* Bg0 = Bt + (size_t)br0 * ldb + spart;
    const ushort* Bg1 = Bt + (size_t)br1 * ldb + spart;
    const ushort* Bg2 = Bt + (size_t)br2 * ldb + spart;
    const ushort* Bg3 = Bt + (size_t)br3 * ldb + spart;
    const int nsteps = K >> 6;

    {
        ushort* as = As + tid * 8;
        ushort* bs = Bs + tid * 8;
        async16(Ag0, as);          async16(Ag1, as + 2048);
        async16(Bg0, bs);          async16(Bg1, bs + 2048);
        async16(Bg2, bs + 4096);   async16(Bg3, bs + 6144);
    }

    int cb = 0;
    for (int c = 0; c < nsteps; ++c) {
        asm volatile("s_waitcnt vmcnt(0)" ::: "memory");
        __builtin_amdgcn_s_barrier();
        asm volatile("" ::: "memory");
        if (c + 1 < nsteps) {
            const int k1 = (c + 1) << 6;
            ushort* as = As + (cb ^ 1) * 4096 + tid * 8;
            ushort* bs = Bs + (cb ^ 1) * 8192 + tid * 8;
            async16(Ag0 + k1, as);          async16(Ag1 + k1, as + 2048);
            async16(Bg0 + k1, bs);          async16(Bg1 + k1, bs + 2048);
            async16(Bg2 + k1, bs + 4096);   async16(Bg3 + k1, bs + 6144);
        }
        const ushort* Ac = As + cb * 4096;
        const ushort* Bc = Bs + cb * 8192;
        #pragma unroll
        for (int ks = 0; ks < 2; ++ks) {
            const int sw = ((ks * 4 + quad) ^ (ln & 7)) * 8;
            short8 af[2], bfr[4];
            #pragma unroll
            for (int t = 0; t < 2; ++t)
                af[t] = *(const short8*)&Ac[(wm + t * 16 + ln) * 64 + sw];
            #pragma unroll
            for (int t = 0; t < 4; ++t)
                bfr[t] = *(const short8*)&Bc[(wn + t * 16 + ln) * 64 + sw];
            __builtin_amdgcn_s_setprio(1);
            #pragma unroll
            for (int i = 0; i < 2; ++i)
                #pragma unroll
                for (int j = 0; j < 4; ++j)
                    acc[i][j] = __builtin_amdgcn_mfma_f32_16x16x32_bf16(af[i], bfr[j], acc[i][j], 0, 0, 0);
            __builtin_amdgcn_s_setprio(0);
        }
        cb ^= 1;
    }

    #pragma unroll
    for (int i = 0; i < 2; ++i) {
        #pragma unroll
        for (int r = 0; r < 4; ++r) {
            const int m = bm + wm + i * 16 + quad * 4 + r;
            #pragma unroll
            for (int j = 0; j < 4; ++j) {
                const int n = bn + wn + j * 16 + ln;
                if (n < N) {
                    if (cbf) ((ushort*)C)[(size_t)m * ldc + n] = f2b(acc[i][j][r]);
                    else     ((float*)C)[(size_t)m * ldc + n] = acc[i][j][r];
                }
            }
        }
    }
}

// ---------------- RMSNorm bf16 in-place (fp32 math), both norms fused ------
__global__ __launch_bounds__(256) void rmsnorm2_bf(
    ushort* __restrict__ x, const void* __restrict__ wq,
    const void* __restrict__ wkv, const int* wflag) {
    const int wbf = *wflag;
    const int which = blockIdx.y;
    const int cols = which ? KLAT : QLAT;
    const void* w = which ? wkv : wq;
    ushort* p = x + (size_t)blockIdx.x * QAC + (which ? QLAT : 0);
    float ss = 0.f;
    for (int i = threadIdx.x; i < cols; i += 256) { float v = b2f(p[i]); ss += v * v; }
    #pragma unroll
    for (int off = 32; off; off >>= 1) ss += __shfl_xor(ss, off);
    __shared__ float red[4];
    const int wid = threadIdx.x >> 6, lane = threadIdx.x & 63;
    if (lane == 0) red[wid] = ss;
    __syncthreads();
    const float tot = red[0] + red[1] + red[2] + red[3];
    const float scale = rsqrtf(tot / (float)cols + 1e-6f);
    for (int i = threadIdx.x; i < cols; i += 256)
        p[i] = f2b(b2f(p[i]) * scale * ld_in(w, i, wbf));
}

// ---------------- RoPE table ----------------
__global__ __launch_bounds__(256) void rope_tab(float* __restrict__ tab) {
    int idx = blockIdx.x * 256 + threadIdx.x;   // SS*32
    int s = idx >> 5, i = idx & 31;
    float inv = powf(10000.0f, -(float)i / 32.0f);
    float sv, cv;
    sincosf((float)s * inv, &sv, &cv);
    tab[idx * 2]     = cv;
    tab[idx * 2 + 1] = sv;
}

__device__ __forceinline__ void rope_block(
    const ushort* __restrict__ src, ushort* __restrict__ dst,
    const float* __restrict__ tb) {
    short8 vin[8];
    #pragma unroll
    for (int t = 0; t < 8; ++t) vin[t] = *(const short8*)(src + t * 8);
    short8 lo[4], hi[4];
    #pragma unroll
    for (int t = 0; t < 4; ++t) {
        #pragma unroll
        for (int j = 0; j < 8; ++j) {
            const int i = t * 8 + j;
            float cv = tb[2 * i], sv = tb[2 * i + 1];
            ushort u0 = ((const ushort*)&vin[(2 * i) >> 3])[(2 * i) & 7];
            ushort u1 = ((const ushort*)&vin[(2 * i + 1) >> 3])[(2 * i + 1) & 7];
            float x0 = b2f(u0), x1 = b2f(u1);
            lo[t][j] = (short)f2b(x0 * cv - x1 * sv);
            hi[t][j] = (short)f2b(x1 * cv + x0 * sv);
        }
    }
    #pragma unroll
    for (int t = 0; t < 4; ++t) {
        *(short8*)(dst + t * 8)      = lo[t];
        *(short8*)(dst + 32 + t * 8) = hi[t];
    }
}

// ---------------- fused post-processing: rope_q | build_kf(+k-rope) | build_vt2
// All three are independent once k-rope is folded into build_kf (reads qac+tab
// directly; redundant per-head rope compute is cheap FMA, removes the kpebf
// roundtrip and a dependent launch). One dispatch, 3712 blocks.
__global__ __launch_bounds__(256) void fuse3(
    ushort* __restrict__ q, const ushort* __restrict__ qac,
    const ushort* __restrict__ kv, ushort* __restrict__ kf,
    ushort* __restrict__ vt2, const float* __restrict__ tab) {
    __shared__ ushort Vl[64 * 136];
    const int b = blockIdx.x;
    const int tid = threadIdx.x;
    if (b < 128) {
        // rope on q_pe: 32768 (s,h) items
        int idx = b * 256 + tid;
        int s = idx >> 4, h = idx & 15;
        ushort* p = q + (size_t)s * QW + h * DQ + DN;
        rope_block(p, p, tab + s * 64);
    } else if (b < 128 + 3072) {
        // build_kf: kf[h][s][192]; parts 16..23 rope k_pe inline from qac
        int idx = (b - 128) * 256 + tid;     // SS*HH*24 items
        int part = idx % 24;
        int rest = idx / 24;
        int h = rest & 15, s = rest >> 4;
        short8 v;
        if (part < 16) {
            v = *(const short8*)(kv + (size_t)s * KVW + h * KVD + part * 8);
        } else {
            const int j8 = part - 16;            // 0..7 output 8-dim segment
            const int seg = j8 & 3;              // input 16-dim segment
            const ushort* cp = qac + (size_t)s * QAC + QLAT + KLAT + seg * 16;
            short8 a = *(const short8*)cp;
            short8 bb = *(const short8*)(cp + 8);
            const float* tb = tab + s * 64 + seg * 16;
            const bool hi = (j8 >= 4);
            #pragma unroll
            for (int jj = 0; jj < 8; ++jj) {
                float cv = tb[2 * jj], sv = tb[2 * jj + 1];
                ushort u0 = (jj < 4) ? (ushort)a[2 * jj]     : (ushort)bb[2 * jj - 8];
                ushort u1 = (jj < 4) ? (ushort)a[2 * jj + 1] : (ushort)bb[2 * jj - 7];
                float x0 = b2f(u0), x1 = b2f(u1);
                v[jj] = (short)f2b(hi ? (x1 * cv + x0 * sv) : (x0 * cv - x1 * sv));
            }
        }
        *(short8*)(kf + ((size_t)h * SS + s) * 192 + part * 8) = v;
    } else {
        // build_vt2
        const int r = b - (128 + 3072);
        const int ck = r & 31, h = r >> 5;
        const int lane = tid & 63, wv = tid >> 6;
        #pragma unroll
        for (int rr = 0; rr < 4; ++rr) {
            int n = rr * 256 + tid;
            int key = n >> 4, part = n & 15;
            short8 v = *(const short8*)(kv + (size_t)(ck * 64 + key) * KVW + h * KVD + DN + part * 8);
            *(short8*)&Vl[key * 136 + part * 8] = v;
        }
        __syncthreads();
        const int ln = lane & 15, quad = lane >> 4;
        ushort* dst = vt2 + (((size_t)h * 32 + ck) * 16) * 512;
        #pragma unroll
        for (int w = 0; w < 4; ++w) {
            int idx2 = wv * 4 + w;
            int kb2 = idx2 >> 3, nb = idx2 & 7;
            short8 v;
            #pragma unroll
            for (int j = 0; j < 8; ++j)
                ((ushort*)&v)[j] = Vl[(kb2 * 32 + quad * 8 + j) * 136 + nb * 16 + ln];
            *(short8*)(dst + (size_t)idx2 * 512 + lane * 8) = v;
        }
    }
}

// ---------------- split-K MFMA flash attention (unchanged) ----------
__global__ __launch_bounds__(256, 2) void attn_mfma2(
    const ushort* __restrict__ qbf, const ushort* __restrict__ kf,
    const ushort* __restrict__ vt2, ushort* __restrict__ opart,
    float* __restrict__ ml) {
    const int seg = blockIdx.x, bq = 31 - blockIdx.y, h = blockIdx.z;
    const int ctot = bq + 1;
    const int c_lo = (seg * ctot) >> 2;
    const int nch = (((seg + 1) * ctot) >> 2) - c_lo;
    if (nch <= 0) return;

    __shared__ ushort Kt[2 * KTSZ];              // 2 x 24576 B
    __shared__ ushort Pt[4][16 * PT_STRIDE];     // 9216 B

    const int tid = threadIdx.x, lane = tid & 63, wl = tid >> 6;
    const int ln = lane & 15, quad = lane >> 4;
    const int qw = bq * 64 + wl * 16;
    const int kstart = c_lo << 6;
    const float scale = 0.07216878364870322f;  // 1/sqrt(192)

    short8 aq[6];
    const ushort* qrow = qbf + (size_t)(qw + ln) * QW + h * DQ;
    #pragma unroll
    for (int kb = 0; kb < 6; ++kb)
        aq[kb] = *(const short8*)(qrow + kb * 32 + quad * 8);

    const ushort* kfh = kf + (size_t)h * SS * 192;
    const ushort* vth2 = vt2 + ((size_t)h * 32 * 16) * 512 + lane * 8;

    const int key_s = tid >> 2;
    const int swp = ((tid & 3) ^ ((tid >> 3) & 3)) * 8;
    const ushort* kg = kfh + (size_t)(kstart + key_s) * 192 + swp;
    const int swq = (quad ^ ((ln >> 1) & 3)) * 8;

    f32x4 oacc[8];
    #pragma unroll
    for (int f = 0; f < 8; ++f) oacc[f] = (f32x4){0.f, 0.f, 0.f, 0.f};
    float mrow[4] = {-INFINITY, -INFINITY, -INFINITY, -INFINITY};
    float lrow[4] = {0.f, 0.f, 0.f, 0.f};

    {
        ushort* kd = Kt + tid * 8;
        #pragma unroll
        for (int i = 0; i < 6; ++i)
            async16(kg + i * 32, kd + i * 2048);
        kg += (size_t)64 * 192;
    }

    for (int c = 0; c < nch; ++c) {
        const int k0 = kstart + (c << 6);
        asm volatile("s_waitcnt vmcnt(0)" ::: "memory");
        __builtin_amdgcn_s_barrier();
        asm volatile("" ::: "memory");
        if (c + 1 < nch) {
            ushort* kd = Kt + ((c + 1) & 1) * KTSZ + tid * 8;
            #pragma unroll
            for (int i = 0; i < 6; ++i)
                async16(kg + i * 32, kd + i * 2048);
            kg += (size_t)64 * 192;
        }
        const ushort* Kcur = Kt + (c & 1) * KTSZ;

        const ushort* vfr = vth2 + (size_t)(k0 >> 6) * 16 * 512;
        short8 bv0[8];
        #pragma unroll
        for (int nb = 0; nb < 8; ++nb)
            bv0[nb] = *(const short8*)(vfr + (size_t)nb * 512);
        f32x4 s[4];
        #pragma unroll
        for (int ns = 0; ns < 4; ++ns) s[ns] = (f32x4){0.f, 0.f, 0.f, 0.f};
        __builtin_amdgcn_s_setprio(1);
        #pragma unroll
        for (int ns = 0; ns < 4; ++ns)
            #pragma unroll
            for (int kb = 0; kb < 6; ++kb) {
                short8 bk = *(const short8*)&Kcur[(kb * 64 + ns * 16 + ln) * 32 + swq];
                s[ns] = __builtin_amdgcn_mfma_f32_16x16x32_bf16(aq[kb], bk, s[ns], 0, 0, 0);
            }
        __builtin_amdgcn_s_setprio(0);
        float pv[4][4], rmax[4];
        #pragma unroll
        for (int r = 0; r < 4; ++r) rmax[r] = -1e30f;
        #pragma unroll
        for (int ns = 0; ns < 4; ++ns)
            #pragma unroll
            for (int r = 0; r < 4; ++r) {
                int key = k0 + ns * 16 + ln;
                int qr = qw + quad * 4 + r;
                float v = s[ns][r] * scale;
                if (key > qr) v = -1e30f;
                pv[ns][r] = v;
                rmax[r] = fmaxf(rmax[r], v);
            }
        #pragma unroll
        for (int off = 8; off; off >>= 1)
            #pragma unroll
            for (int r = 0; r < 4; ++r)
                rmax[r] = fmaxf(rmax[r], __shfl_xor(rmax[r], off));
        float alpha[4], psum[4];
        #pragma unroll
        for (int r = 0; r < 4; ++r) {
            float mnew = fmaxf(mrow[r], rmax[r]);
            alpha[r] = __expf(mrow[r] - mnew);
            mrow[r] = mnew;
        }
        #pragma unroll
        for (int ns = 0; ns < 4; ++ns)
            #pragma unroll
            for (int r = 0; r < 4; ++r)
                pv[ns][r] = __expf(pv[ns][r] - mrow[r]);
        #pragma unroll
        for (int r = 0; r < 4; ++r)
            psum[r] = (pv[0][r] + pv[1][r]) + (pv[2][r] + pv[3][r]);
        #pragma unroll
        for (int off = 8; off; off >>= 1)
            #pragma unroll
            for (int r = 0; r < 4; ++r)
                psum[r] += __shfl_xor(psum[r], off);
        #pragma unroll
        for (int r = 0; r < 4; ++r) lrow[r] = lrow[r] * alpha[r] + psum[r];
        #pragma unroll
        for (int f = 0; f < 8; ++f)
            #pragma unroll
            for (int r = 0; r < 4; ++r) oacc[f][r] *= alpha[r];
        #pragma unroll
        for (int ns = 0; ns < 4; ++ns)
            #pragma unroll
            for (int r = 0; r < 4; ++r)
                Pt[wl][(quad * 4 + r) * PT_STRIDE + ns * 16 + ln] = f2b(pv[ns][r]);
        short8 bv1[8];
        #pragma unroll
        for (int nb = 0; nb < 8; ++nb)
            bv1[nb] = *(const short8*)(vfr + (size_t)(8 + nb) * 512);
        short8 pa0 = *(const short8*)&Pt[wl][ln * PT_STRIDE + quad * 8];
        short8 pa1 = *(const short8*)&Pt[wl][ln * PT_STRIDE + 32 + quad * 8];
        __builtin_amdgcn_s_setprio(1);
        #pragma unroll
        for (int nb = 0; nb < 8; ++nb)
            oacc[nb] = __builtin_amdgcn_mfma_f32_16x16x32_bf16(pa0, bv0[nb], oacc[nb], 0, 0, 0);
        #pragma unroll
        for (int nb = 0; nb < 8; ++nb)
            oacc[nb] = __builtin_amdgcn_mfma_f32_16x16x32_bf16(pa1, bv1[nb], oacc[nb], 0, 0, 0);
        __builtin_amdgcn_s_setprio(0);
    }

    const size_t pbase = (((size_t)h * 32 + bq) * NSEG + seg) * 64;
    #pragma unroll
    for (int nb = 0; nb < 8; ++nb)
        #pragma unroll
        for (int r = 0; r < 4; ++r)
            opart[(pbase + wl * 16 + quad * 4 + r) * 128 + nb * 16 + ln] = f2b(oacc[nb][r]);
    if (ln == 0) {
        #pragma unroll
        for (int r = 0; r < 4; ++r) {
            ml[(pbase + wl * 16 + quad * 4 + r) * 2]     = mrow[r];
            ml[(pbase + wl * 16 + quad * 4 + r) * 2 + 1] = lrow[r];
        }
    }
}

// ---------------- merge partials -> obf ----------------
__global__ __launch_bounds__(256) void merge_attn(
    const ushort* __restrict__ opart, const float* __restrict__ ml,
    ushort* __restrict__ obf) {
    const int q = blockIdx.x;
    const int bq = q >> 6, row = q & 63;
    const int ctot = bq + 1;
    const int t = threadIdx.x;
    #pragma unroll
    for (int pp = 0; pp < 8; ++pp) {
        int idx = pp * 256 + t;            // 0..2047 = h*128 + d
        int h = idx >> 7, d = idx & 127;
        size_t rbase = (((size_t)h * 32 + bq) * NSEG) * 64 + row;  // + s*64
        float M = -1e30f;
        #pragma unroll
        for (int s = 0; s < NSEG; ++s) {
            if ((((s + 1) * ctot) >> 2) > ((s * ctot) >> 2))
                M = fmaxf(M, ml[(rbase + (size_t)s * 64) * 2]);
        }
        float L = 0.f, acc = 0.f;
        #pragma unroll
        for (int s = 0; s < NSEG; ++s) {
            if ((((s + 1) * ctot) >> 2) > ((s * ctot) >> 2)) {
                size_t ri = rbase + (size_t)s * 64;
                float w = __expf(ml[ri * 2] - M);
                L += w * ml[ri * 2 + 1];
                acc += w * b2f(opart[ri * 128 + d]);
            }
        }
        obf[(size_t)q * OW + h * DV + d] = f2b(acc / L);
    }
}

// ---------------- launch ----------------
extern "C" void kernel_launch(void* const* d_in, const int* in_sizes, int n_in,
                              void* d_out, int out_size, void* d_ws, size_t ws_size,
                              hipStream_t stream) {
    const void* x       = d_in[0];
    const void* w_q_a   = d_in[1];
    const void* q_a_ln  = d_in[2];
    const void* w_q_b   = d_in[3];
    const void* w_kv_a  = d_in[4];
    const void* kv_a_ln = d_in[5];
    const void* w_kv_b  = d_in[6];
    const void* w_out   = d_in[7];

    char* ws = (char*)d_ws;
    int*    flag  = (int*)ws;
    ushort* qbf   = (ushort*)(ws + 256);             // S*QW
    ushort* obf   = qbf   + (size_t)SS * QW;         // S*OW
    ushort* wqat  = obf   + (size_t)SS * OW;         // QLAT*EE  } contiguous ->
    ushort* wkvat = wqat  + (size_t)QLAT * EE;       // CKVW*EE  } merged Bt[2112][EE]
    ushort* wqbt  = wkvat + (size_t)CKVW * EE;       // QW*QLAT
    ushort* wkvbt = wqbt  + (size_t)QW * QLAT;       // KVW*KLAT
    ushort* woutt = wkvbt + (size_t)KVW * KLAT;      // EE*OW
    ushort* kf    = woutt + (size_t)EE * OW;         // HH*SS*192
    ushort* vt2   = kf    + (size_t)HH * SS * 192;   // HH*SS*DV (frag-ordered)
    float*  ml    = (float*)(vt2 + (size_t)HH * SS * DV);  // HH*32*NSEG*64*2 floats
    // overlay zone (all dead before attention writes opart):
    ushort* qac   = (ushort*)(ml + (size_t)HH * 32 * NSEG * 64 * 2);  // S*QAC
    ushort* xbf   = qac   + (size_t)SS * QAC;        // S*EE
    ushort* kvbf  = xbf   + (size_t)SS * EE;         // S*KVW
    ushort* kpebf = kvbf  + (size_t)SS * KVW;        // S*DR (unused in v6; kept for layout)
    float*  rtab  = (float*)(kpebf + (size_t)SS * DR);  // SS*32*2 floats (cos,sin)
    ushort* opart = qac;  // HH*32*NSEG*64*128 halfs <= overlay span (17.04M)

    detect_dtype<<<1, 1, 0, stream>>>((const unsigned int*)q_a_ln, flag);
    rope_tab<<<SS * 32 / 256, 256, 0, stream>>>(rtab);

    conv_x_bf<<<(SS * EE / 4 + 255) / 256, 256, 0, stream>>>(x, xbf, SS * EE, flag);
    transpose5_bf<<<dim3(64, 32, 5), 256, 0, stream>>>(
        w_q_a, w_kv_a, w_q_b, w_kv_b, w_out,
        wqat, wkvat, wqbt, wkvbt, woutt, flag);

    // qac = x @ [w_q_a | w_kv_a]  (2048 x 2112, K=2048), merged, 544 blocks
    gemm_bf64<<<dim3((QAC + 127) / 128, SS / 64), 256, 0, stream>>>(
        xbf, wqat, qac, QAC, EE, EE, EE, QAC, 1, nullptr);

    rmsnorm2_bf<<<dim3(SS, 2), 256, 0, stream>>>(qac, q_a_ln, kv_a_ln, flag);

    // qbf = qa_norm @ w_q_b  AND  kvbf = ckv_norm @ w_kv_b, one launch
    gemm_qkv<<<dim3(KVW / 128, SS / 128, 2), 256, 0, stream>>>(
        qac, wqbt, wkvbt, qbf, kvbf);

    // rope_q + build_kf(+k-rope) + build_vt2, one launch
    fuse3<<<128 + 3072 + 512, 256, 0, stream>>>(qbf, qac, kvbf, kf, vt2, rtab);

    attn_mfma2<<<dim3(NSEG, SS / 64, HH), 256, 0, stream>>>(qbf, kf, vt2, opart, ml);
    merge_attn<<<SS, 256, 0, stream>>>(opart, ml, obf);

    // out = o @ w_out (2048x2048, K=2048), 512 blocks via 64-tile
    gemm_bf64<<<dim3(EE / 128, SS / 64), 256, 0, stream>>>(
        obf, woutt, d_out, EE, OW, OW, OW, EE, 2, flag);
}